// Round 3
// baseline (232.892 us; speedup 1.0000x reference)
//
#include <hip/hip_runtime.h>
#include <math.h>

#define BB   2
#define CFI  32
#define NN   36864          // 192*192
#define NUMM 16

// workspace: Y at ws[0..], Z at ws[ZOFS..]  (point-major [B*N][32] each)
#define ZOFS (BB * NN * CFI)

typedef __attribute__((ext_vector_type(8))) short short8;   // 8 bf16 (4 VGPRs)
typedef __attribute__((ext_vector_type(4))) float f4;       // 4 f32
typedef __attribute__((ext_vector_type(16))) float f16v;    // 16 f32 (32x32 acc)

static __device__ __forceinline__ f16v mm32(short8 a, short8 b, f16v c) {
    return __builtin_amdgcn_mfma_f32_32x32x16_bf16(a, b, c, 0, 0, 0);
}

// tanh-form gelu: x * sigmoid(1.595769x + 0.0713548x^3), exp2-folded.
static __device__ __forceinline__ float gelu_fast(float x) {
    const float x2  = x * x;
    const float q   = fmaf(-0.10294310f, x2, -2.30211813f);
    const float e   = exp2f(q * x);
    const float r   = __builtin_amdgcn_rcpf(e + 1.0f);
    return x * r;
}

static __device__ __forceinline__ unsigned bf16_rne_bits(float x) {
    unsigned u = __builtin_bit_cast(unsigned, x);
    return u + 0x7fffu + ((u >> 16) & 1u);
}
static __device__ __forceinline__ void split_pack(float x0, float x1,
                                                  unsigned& hi, unsigned& lo) {
    unsigned r0 = bf16_rne_bits(x0);
    unsigned r1 = bf16_rne_bits(x1);
    float h0 = __builtin_bit_cast(float, r0 & 0xffff0000u);
    float h1 = __builtin_bit_cast(float, r1 & 0xffff0000u);
    hi = (r0 >> 16) | (r1 & 0xffff0000u);
    unsigned s0 = bf16_rne_bits(x0 - h0);
    unsigned s1 = bf16_rne_bits(x1 - h1);
    lo = (s0 >> 16) | (s1 & 0xffff0000u);
}

// cheap round-half-up bf16 pair pack (activations)
static __device__ __forceinline__ unsigned pack2(float a, float b) {
    unsigned ua = __builtin_bit_cast(unsigned, a) + 0x8000u;
    unsigned ub = __builtin_bit_cast(unsigned, b) + 0x8000u;
    return (ua >> 16) | (ub & 0xffff0000u);
}

union UV { unsigned u[4]; short8 v; };

// ---- kernel A: per-point Y/Z precompute (layer-1 split) -- unchanged ------
__global__ __launch_bounds__(256) void yz_kernel(
    const float* __restrict__ If, const float* __restrict__ Pf,
    const float* __restrict__ W1, const float* __restrict__ g1,
    const float* __restrict__ b1, const float* __restrict__ m1,
    const float* __restrict__ v1,
    float* __restrict__ wsYZ)
{
    __shared__ float wy[1024], wz[1024], wp[32], bt1[32];
    for (int i = threadIdx.x; i < 1024; i += 256) {
        int o = i >> 5, c = i & 31;
        float inv = g1[o] * rsqrtf(v1[o] + 1e-5f);
        wy[i] = W1[o * 67 + c]      * inv;
        wz[i] = W1[o * 67 + 32 + c] * inv;
    }
    if (threadIdx.x < 32) {
        int o = threadIdx.x;
        float inv = g1[o] * rsqrtf(v1[o] + 1e-5f);
        wp[o]  = W1[o * 67 + 64] * inv;
        bt1[o] = b1[o] - m1[o] * inv;
    }
    __syncthreads();

    const int r  = threadIdx.x & 3;
    const int p  = blockIdx.x * 64 + (threadIdx.x >> 2);
    const int b  = p / NN, n = p - b * NN;
    const int o0 = r * 8;
    const float* ifp = If + (size_t)b * CFI * NN + n;

    float v[32];
#pragma unroll
    for (int c = 0; c < 32; c++) v[c] = ifp[(size_t)c * NN];
    const float pf = Pf[p];

    float accY[8], accZ[8];
#pragma unroll
    for (int j = 0; j < 8; j++) {
        const float4* wyr = (const float4*)&wy[(o0 + j) * 32];
        const float4* wzr = (const float4*)&wz[(o0 + j) * 32];
        float ay = bt1[o0 + j];
        float az = wp[o0 + j] * pf;
#pragma unroll
        for (int c4 = 0; c4 < 8; c4++) {
            float4 a = wyr[c4], z = wzr[c4];
            ay = fmaf(a.x, v[4 * c4 + 0], ay);  az = fmaf(z.x, v[4 * c4 + 0], az);
            ay = fmaf(a.y, v[4 * c4 + 1], ay);  az = fmaf(z.y, v[4 * c4 + 1], az);
            ay = fmaf(a.z, v[4 * c4 + 2], ay);  az = fmaf(z.z, v[4 * c4 + 2], az);
            ay = fmaf(a.w, v[4 * c4 + 3], ay);  az = fmaf(z.w, v[4 * c4 + 3], az);
        }
        accY[j] = ay; accZ[j] = az;
    }

    float4* yp = (float4*)(wsYZ + (size_t)p * 32 + o0);
    float4* zp = (float4*)(wsYZ + ZOFS + (size_t)p * 32 + o0);
    yp[0] = make_float4(accY[0], accY[1], accY[2], accY[3]);
    yp[1] = make_float4(accY[4], accY[5], accY[6], accY[7]);
    zp[0] = make_float4(accZ[0], accZ[1], accZ[2], accZ[3]);
    zp[1] = make_float4(accZ[4], accZ[5], accZ[6], accZ[7]);
}

// ---- kernel B: 32x32x16 MFMA MLP, 2 points per wave-pass ------------------
// r15: phi(g,j) = 4g + (j&3) + 8*(j>>2) k-relabeling -> relayout = 8 pack2,
// zero cross-lane ops. (Verified: absmax 0.0078.)
// r16: (256,5) forced ~102-reg budget; 2-pt/pass working set is ~90-110 regs
// -> 27.9 MB/dispatch scratch spill (WRITE_SIZE), ate the whole VALU win.
// (256,4) -> 128-reg budget, no spill; measured occupancy was already 45%
// so 4 waves/SIMD (50%) gives up nothing.
#define LAYER(Lc, BIN0, BIN1, ACCV)                                           \
    {                                                                         \
        const f4 bq0 = *(const f4*)&btl[(Lc) * 32 +      4 * hi + 4 * io];    \
        const f4 bq1 = *(const f4*)&btl[(Lc) * 32 +  8 + 4 * hi + 4 * io];    \
        const f4 bq2 = *(const f4*)&btl[(Lc) * 32 + 16 + 4 * hi + 4 * io];    \
        const f4 bq3 = *(const f4*)&btl[(Lc) * 32 + 24 + 4 * hi + 4 * io];    \
        ACCV[0]  = bq0[0]; ACCV[1]  = bq0[1]; ACCV[2]  = bq0[2]; ACCV[3]  = bq0[3]; \
        ACCV[4]  = bq1[0]; ACCV[5]  = bq1[1]; ACCV[6]  = bq1[2]; ACCV[7]  = bq1[3]; \
        ACCV[8]  = bq2[0]; ACCV[9]  = bq2[1]; ACCV[10] = bq2[2]; ACCV[11] = bq2[3]; \
        ACCV[12] = bq3[0]; ACCV[13] = bq3[1]; ACCV[14] = bq3[2]; ACCV[15] = bq3[3]; \
        short8 Af;                                                            \
        Af = *(const short8*)&wfrag[(Lc)][0][1][lane + io][0];                \
        ACCV = mm32(Af, BIN0.v, ACCV);                                        \
        Af = *(const short8*)&wfrag[(Lc)][0][0][lane + io][0];                \
        ACCV = mm32(Af, BIN0.v, ACCV);                                        \
        Af = *(const short8*)&wfrag[(Lc)][1][1][lane + io][0];                \
        ACCV = mm32(Af, BIN1.v, ACCV);                                        \
        Af = *(const short8*)&wfrag[(Lc)][1][0][lane + io][0];                \
        ACCV = mm32(Af, BIN1.v, ACCV);                                        \
    }

// C regs (gelu'd, register order == phi order) -> next-layer B fragments.
#define RELAYOUT(SRC, B0V, B1V)                                               \
    {                                                                         \
        B0V.u[0] = pack2(SRC[0],  SRC[1]);                                    \
        B0V.u[1] = pack2(SRC[2],  SRC[3]);                                    \
        B0V.u[2] = pack2(SRC[4],  SRC[5]);                                    \
        B0V.u[3] = pack2(SRC[6],  SRC[7]);                                    \
        B1V.u[0] = pack2(SRC[8],  SRC[9]);                                    \
        B1V.u[1] = pack2(SRC[10], SRC[11]);                                   \
        B1V.u[2] = pack2(SRC[12], SRC[13]);                                   \
        B1V.u[3] = pack2(SRC[14], SRC[15]);                                   \
    }

__global__ __launch_bounds__(256, 4) void main_kernel(
    const float* __restrict__ Pf, const float* __restrict__ Of,
    const int* __restrict__ args,
    const float* __restrict__ W1, const float* __restrict__ g1,
    const float* __restrict__ v1,
    const float* __restrict__ W2, const float* __restrict__ g2,
    const float* __restrict__ b2, const float* __restrict__ m2,
    const float* __restrict__ v2,
    const float* __restrict__ W3, const float* __restrict__ g3,
    const float* __restrict__ b3, const float* __restrict__ m3,
    const float* __restrict__ v3,
    const float* __restrict__ W4, const float* __restrict__ g4,
    const float* __restrict__ b4, const float* __restrict__ m4,
    const float* __restrict__ v4,
    const float* __restrict__ Wc, const float* __restrict__ bc,
    const float* __restrict__ ws, float* __restrict__ out)
{
    __shared__ __align__(16) unsigned wfrag[3][2][2][64][4]; // L,khalf,hi/lo,lane,pair
    __shared__ __align__(16) float btl[3 * 32];   // BN beta by [L][ch]
    __shared__ __align__(16) float wch[3 * 32];   // Wc rows A,B,O by ch
    __shared__ __align__(16) float w1t[2 * 32];   // W1 cols 65,66 folded, by ch
    __shared__ float bcs[3];
    __shared__ int   izs;

    const float* Ws[3] = {W2, W3, W4};
    const float* gs[3] = {g2, g3, g4};
    const float* vs[3] = {v2, v3, v4};
    const float* bs[3] = {b2, b3, b4};
    const float* ms[3] = {m2, m3, m4};

    for (int idx = threadIdx.x; idx < 1536; idx += 256) {
        int pp  = idx & 3;
        int ln  = (idx >> 2) & 63;
        int kh  = (idx >> 8) & 1;
        int L   = idx >> 9;
        int row = ln & 31;
        int g   = ln >> 5;
        // phi(g, e) = 4g + (e&3) + 8*(e>>2); pair pp covers elems 2pp, 2pp+1
        int k   = kh * 16 + 4 * g + 2 * (pp & 1) + 8 * (pp >> 1);
        float inv = gs[L][row] * rsqrtf(vs[L][row] + 1e-5f);
        float w0 = Ws[L][row * 32 + k]     * inv;
        float w1 = Ws[L][row * 32 + k + 1] * inv;
        unsigned hiw, low;
        split_pack(w0, w1, hiw, low);
        wfrag[L][kh][0][ln][pp] = hiw;
        wfrag[L][kh][1][ln][pp] = low;
    }
    if (threadIdx.x < 96) {
        int L = threadIdx.x >> 5, ch = threadIdx.x & 31;
        btl[threadIdx.x] = bs[L][ch] - ms[L][ch] * (gs[L][ch] * rsqrtf(vs[L][ch] + 1e-5f));
        wch[threadIdx.x] = Wc[L * 32 + ch];
    }
    if (threadIdx.x < 64) {
        int t = threadIdx.x >> 5, ch = threadIdx.x & 31;
        float i1 = g1[ch] * rsqrtf(v1[ch] + 1e-5f);
        w1t[threadIdx.x] = W1[ch * 67 + 65 + t] * i1;
    }
    if (threadIdx.x < 3) bcs[threadIdx.x] = bc[threadIdx.x];
    if (threadIdx.x == 0) izs = (int)(args[0] >> 16);   // == 0, opaque
    __syncthreads();

    const int lane  = threadIdx.x & 63;
    const int wid   = threadIdx.x >> 6;
    const int m     = lane & 15;          // m-index (softmax axis)
    const int pt    = (lane >> 4) & 1;    // which of the 2 points in the pass
    const int hi    = lane >> 5;          // k-group
    const int q4    = hi << 2;            // 4*hi
    const int izero = izs;                // 0, compiler-opaque

#pragma unroll 1
    for (int i = 0; i < 2; i++) {
        const int io = i & izero;                         // 0 every iter, unprovable
        const int C  = blockIdx.x * 16 + wid * 4 + i * 2 + pt;
        const int b  = (C >= NN) ? 1 : 0;
        const int n  = C - b * NN;

        const int   aIdx = args[(b * NUMM + m) * NN + n];
        const float of0v = Of[((b * 2 + 0) * NUMM + m) * NN + n];
        const float of1v = Of[((b * 2 + 1) * NUMM + m) * NN + n];
        const float pfg  = Pf[b * NN + aIdx];

        // this lane supplies channels {4hi..4hi+3, 8+4hi.., 16+4hi.., 24+4hi..}
        const f4* yb = (const f4*)(ws + (size_t)(b * NN + n) * 32);
        const f4* zb = (const f4*)(ws + ZOFS + (size_t)(b * NN + aIdx) * 32);
        f4 y0 = yb[hi], y1 = yb[2 + hi], y2 = yb[4 + hi], y3 = yb[6 + hi];
        f4 z0 = zb[hi], z1 = zb[2 + hi], z2 = zb[4 + hi], z3 = zb[6 + hi];

        const f4 wa0 = *(const f4*)&w1t[q4 + 4 * io];
        const f4 wa1 = *(const f4*)&w1t[8 + q4 + 4 * io];
        const f4 wa2 = *(const f4*)&w1t[16 + q4 + 4 * io];
        const f4 wa3 = *(const f4*)&w1t[24 + q4 + 4 * io];
        const f4 wb0 = *(const f4*)&w1t[32 + q4 + 4 * io];
        const f4 wb1 = *(const f4*)&w1t[40 + q4 + 4 * io];
        const f4 wb2 = *(const f4*)&w1t[48 + q4 + 4 * io];
        const f4 wb3 = *(const f4*)&w1t[56 + q4 + 4 * io];

        // ---- layer 1: h1 = gelu(Y+Z+of terms) -> directly the B fragments ----
        float x[16];
#pragma unroll
        for (int j = 0; j < 4; j++) {
            x[j]      = fmaf(of1v, wb0[j], fmaf(of0v, wa0[j], y0[j] + z0[j]));
            x[4 + j]  = fmaf(of1v, wb1[j], fmaf(of0v, wa1[j], y1[j] + z1[j]));
            x[8 + j]  = fmaf(of1v, wb2[j], fmaf(of0v, wa2[j], y2[j] + z2[j]));
            x[12 + j] = fmaf(of1v, wb3[j], fmaf(of0v, wa3[j], y3[j] + z3[j]));
        }
#pragma unroll
        for (int j = 0; j < 16; j++) x[j] = gelu_fast(x[j]);
        UV B0, B1;
        RELAYOUT(x, B0, B1);

        // ---- layer 2 ----
        f16v acc;
        LAYER(0, B0, B1, acc);
        float h2g[16];
#pragma unroll
        for (int r = 0; r < 16; r++) h2g[r] = gelu_fast(acc[r]);
        RELAYOUT(h2g, B0, B1);

        // ---- layer 3 ----
        LAYER(1, B0, B1, acc);
        float h3g[16];
#pragma unroll
        for (int r = 0; r < 16; r++) h3g[r] = gelu_fast(acc[r]);
        RELAYOUT(h3g, B0, B1);

        // ---- layer 4 + residual + head (all in C layout) ----
        LAYER(2, B0, B1, acc);

        float pa = 0.0f, pb = 0.0f, po = 0.0f;
#pragma unroll
        for (int q = 0; q < 4; q++) {
            const f4 wAq = *(const f4*)&wch[      8 * q + q4 + 4 * io];
            const f4 wBq = *(const f4*)&wch[32 +  8 * q + q4 + 4 * io];
            const f4 wOq = *(const f4*)&wch[64 +  8 * q + q4 + 4 * io];
#pragma unroll
            for (int r2 = 0; r2 < 4; r2++) {
                float xf = gelu_fast(h2g[4 * q + r2] + acc[4 * q + r2]);
                pa = fmaf(wAq[r2], xf, pa);
                pb = fmaf(wBq[r2], xf, pb);
                po = fmaf(wOq[r2], xf, po);
            }
        }
        // partner half (lane^32) holds the other 16 channels
        pa += __shfl_xor(pa, 32, 64);
        pb += __shfl_xor(pb, 32, 64);
        po += __shfl_xor(po, 32, 64);

        const float alpha = pa + bcs[0];
        const float beta_ = pb + bcs[1];
        const float omega = po + bcs[2];
        const float val = fmaf(alpha + 1.0f, pfg, beta_);

        // softmax over the 16 m's (within each 16-lane group)
        float mx = omega;
#pragma unroll
        for (int s = 1; s < 16; s <<= 1) mx = fmaxf(mx, __shfl_xor(mx, s, 64));
        const float e = __expf(omega - mx);
        float S = e, T = val * e;
#pragma unroll
        for (int s = 1; s < 16; s <<= 1) {
            S += __shfl_xor(S, s, 64);
            T += __shfl_xor(T, s, 64);
        }
        if ((lane & 15) == 0 && lane < 32)
            out[b * NN + n] = T * __builtin_amdgcn_rcpf(S);
    }
}

// ---- launcher ---------------------------------------------------------------
extern "C" void kernel_launch(void* const* d_in, const int* in_sizes, int n_in,
                              void* d_out, int out_size, void* d_ws, size_t ws_size,
                              hipStream_t stream) {
    const float* If    = (const float*)d_in[0];
    const float* Pf    = (const float*)d_in[1];
    const float* Of    = (const float*)d_in[2];
    const int*   args  = (const int*)d_in[3];
    const float* W1    = (const float*)d_in[4];
    const float* g1    = (const float*)d_in[5];
    const float* b1    = (const float*)d_in[6];
    const float* m1    = (const float*)d_in[7];
    const float* v1    = (const float*)d_in[8];
    const float* W2    = (const float*)d_in[9];
    const float* g2    = (const float*)d_in[10];
    const float* b2    = (const float*)d_in[11];
    const float* m2    = (const float*)d_in[12];
    const float* v2    = (const float*)d_in[13];
    const float* W3    = (const float*)d_in[14];
    const float* g3    = (const float*)d_in[15];
    const float* b3    = (const float*)d_in[16];
    const float* m3    = (const float*)d_in[17];
    const float* v3    = (const float*)d_in[18];
    const float* W4    = (const float*)d_in[19];
    const float* g4    = (const float*)d_in[20];
    const float* b4    = (const float*)d_in[21];
    const float* m4    = (const float*)d_in[22];
    const float* v4    = (const float*)d_in[23];
    const float* Wc    = (const float*)d_in[24];
    const float* bc    = (const float*)d_in[25];

    float* ws  = (float*)d_ws;
    float* out = (float*)d_out;

    yz_kernel<<<(BB * NN) / 64, 256, 0, stream>>>(
        If, Pf, W1, g1, b1, m1, v1, ws);

    main_kernel<<<(BB * NN) / 16, 256, 0, stream>>>(
        Pf, Of, args,
        W1, g1, v1,
        W2, g2, b2, m2, v2,
        W3, g3, b3, m3, v3,
        W4, g4, b4, m4, v4,
        Wc, bc, ws, out);
}

// Round 4
// 227.351 us; speedup vs baseline: 1.0244x; 1.0244x over previous
//
#include <hip/hip_runtime.h>
#include <math.h>

#define BB   2
#define CFI  32
#define NN   36864          // 192*192
#define NUMM 16

// workspace: Y at ws[0..], Z at ws[ZOFS..]  (point-major [B*N][32] each)
#define ZOFS (BB * NN * CFI)

typedef __attribute__((ext_vector_type(8))) short short8;   // 8 bf16 (4 VGPRs)
typedef __attribute__((ext_vector_type(4))) float f4;       // 4 f32
typedef __attribute__((ext_vector_type(16))) float f16v;    // 16 f32 (32x32 acc)

static __device__ __forceinline__ f16v mm32(short8 a, short8 b, f16v c) {
    return __builtin_amdgcn_mfma_f32_32x32x16_bf16(a, b, c, 0, 0, 0);
}

// tanh-form gelu: x * sigmoid(1.595769x + 0.0713548x^3), exp2-folded.
static __device__ __forceinline__ float gelu_fast(float x) {
    const float x2  = x * x;
    const float q   = fmaf(-0.10294310f, x2, -2.30211813f);
    const float e   = exp2f(q * x);
    const float r   = __builtin_amdgcn_rcpf(e + 1.0f);
    return x * r;
}

static __device__ __forceinline__ unsigned bf16_rne_bits(float x) {
    unsigned u = __builtin_bit_cast(unsigned, x);
    return u + 0x7fffu + ((u >> 16) & 1u);
}
static __device__ __forceinline__ void split_pack(float x0, float x1,
                                                  unsigned& hi, unsigned& lo) {
    unsigned r0 = bf16_rne_bits(x0);
    unsigned r1 = bf16_rne_bits(x1);
    float h0 = __builtin_bit_cast(float, r0 & 0xffff0000u);
    float h1 = __builtin_bit_cast(float, r1 & 0xffff0000u);
    hi = (r0 >> 16) | (r1 & 0xffff0000u);
    unsigned s0 = bf16_rne_bits(x0 - h0);
    unsigned s1 = bf16_rne_bits(x1 - h1);
    lo = (s0 >> 16) | (s1 & 0xffff0000u);
}

// cheap round-half-up bf16 pair pack (activations)
static __device__ __forceinline__ unsigned pack2(float a, float b) {
    unsigned ua = __builtin_bit_cast(unsigned, a) + 0x8000u;
    unsigned ub = __builtin_bit_cast(unsigned, b) + 0x8000u;
    return (ua >> 16) | (ub & 0xffff0000u);
}

union UV { unsigned u[4]; short8 v; };

// ---- kernel A: per-point Y/Z precompute (layer-1 split) -- unchanged ------
__global__ __launch_bounds__(256) void yz_kernel(
    const float* __restrict__ If, const float* __restrict__ Pf,
    const float* __restrict__ W1, const float* __restrict__ g1,
    const float* __restrict__ b1, const float* __restrict__ m1,
    const float* __restrict__ v1,
    float* __restrict__ wsYZ)
{
    __shared__ float wy[1024], wz[1024], wp[32], bt1[32];
    for (int i = threadIdx.x; i < 1024; i += 256) {
        int o = i >> 5, c = i & 31;
        float inv = g1[o] * rsqrtf(v1[o] + 1e-5f);
        wy[i] = W1[o * 67 + c]      * inv;
        wz[i] = W1[o * 67 + 32 + c] * inv;
    }
    if (threadIdx.x < 32) {
        int o = threadIdx.x;
        float inv = g1[o] * rsqrtf(v1[o] + 1e-5f);
        wp[o]  = W1[o * 67 + 64] * inv;
        bt1[o] = b1[o] - m1[o] * inv;
    }
    __syncthreads();

    const int r  = threadIdx.x & 3;
    const int p  = blockIdx.x * 64 + (threadIdx.x >> 2);
    const int b  = p / NN, n = p - b * NN;
    const int o0 = r * 8;
    const float* ifp = If + (size_t)b * CFI * NN + n;

    float v[32];
#pragma unroll
    for (int c = 0; c < 32; c++) v[c] = ifp[(size_t)c * NN];
    const float pf = Pf[p];

    float accY[8], accZ[8];
#pragma unroll
    for (int j = 0; j < 8; j++) {
        const float4* wyr = (const float4*)&wy[(o0 + j) * 32];
        const float4* wzr = (const float4*)&wz[(o0 + j) * 32];
        float ay = bt1[o0 + j];
        float az = wp[o0 + j] * pf;
#pragma unroll
        for (int c4 = 0; c4 < 8; c4++) {
            float4 a = wyr[c4], z = wzr[c4];
            ay = fmaf(a.x, v[4 * c4 + 0], ay);  az = fmaf(z.x, v[4 * c4 + 0], az);
            ay = fmaf(a.y, v[4 * c4 + 1], ay);  az = fmaf(z.y, v[4 * c4 + 1], az);
            ay = fmaf(a.z, v[4 * c4 + 2], ay);  az = fmaf(z.z, v[4 * c4 + 2], az);
            ay = fmaf(a.w, v[4 * c4 + 3], ay);  az = fmaf(z.w, v[4 * c4 + 3], az);
        }
        accY[j] = ay; accZ[j] = az;
    }

    float4* yp = (float4*)(wsYZ + (size_t)p * 32 + o0);
    float4* zp = (float4*)(wsYZ + ZOFS + (size_t)p * 32 + o0);
    yp[0] = make_float4(accY[0], accY[1], accY[2], accY[3]);
    yp[1] = make_float4(accY[4], accY[5], accY[6], accY[7]);
    zp[0] = make_float4(accZ[0], accZ[1], accZ[2], accZ[3]);
    zp[1] = make_float4(accZ[4], accZ[5], accZ[6], accZ[7]);
}

// ---- kernel B: 32x32x16 MFMA MLP, 2 pts/pass, 4-deep gather pipeline ------
// r15: phi(g,j) k-relabeling -> relayout = 8 pack2, zero cross-lane ops.
// r16: (256,4) killed the 28MB spill (WRITE 0.29MB) but dur unchanged
//      -> NOT VALU/memory-traffic bound. Issue math: ~830 VALU/iter
//      = ~28us of pure issue vs 103us measured => latency-bound; VALUBusy
//      87% must be CU-level. Exposed chain: args gather (~600cy) ->
//      Z[aIdx]/Pf[aIdx] gathers (~600-900cy) -> L1, at 4 waves/SIMD.
// r17: software-pipeline gathers across 4 iterations/wave (32 pts/block):
//      args for i+1 issued at top of i; y/of for i+1 after L2; z/pf for
//      i+1 after L3 (args landed by then). Iterations 1..3 start with
//      operands in registers. Math per point bit-identical.
#define LAYER(Lc, BIN0, BIN1, ACCV)                                           \
    {                                                                         \
        const f4 bq0 = *(const f4*)&btl[(Lc) * 32 +      4 * hi + 4 * io];    \
        const f4 bq1 = *(const f4*)&btl[(Lc) * 32 +  8 + 4 * hi + 4 * io];    \
        const f4 bq2 = *(const f4*)&btl[(Lc) * 32 + 16 + 4 * hi + 4 * io];    \
        const f4 bq3 = *(const f4*)&btl[(Lc) * 32 + 24 + 4 * hi + 4 * io];    \
        ACCV[0]  = bq0[0]; ACCV[1]  = bq0[1]; ACCV[2]  = bq0[2]; ACCV[3]  = bq0[3]; \
        ACCV[4]  = bq1[0]; ACCV[5]  = bq1[1]; ACCV[6]  = bq1[2]; ACCV[7]  = bq1[3]; \
        ACCV[8]  = bq2[0]; ACCV[9]  = bq2[1]; ACCV[10] = bq2[2]; ACCV[11] = bq2[3]; \
        ACCV[12] = bq3[0]; ACCV[13] = bq3[1]; ACCV[14] = bq3[2]; ACCV[15] = bq3[3]; \
        short8 Af;                                                            \
        Af = *(const short8*)&wfrag[(Lc)][0][1][lane + io][0];                \
        ACCV = mm32(Af, BIN0.v, ACCV);                                        \
        Af = *(const short8*)&wfrag[(Lc)][0][0][lane + io][0];                \
        ACCV = mm32(Af, BIN0.v, ACCV);                                        \
        Af = *(const short8*)&wfrag[(Lc)][1][1][lane + io][0];                \
        ACCV = mm32(Af, BIN1.v, ACCV);                                        \
        Af = *(const short8*)&wfrag[(Lc)][1][0][lane + io][0];                \
        ACCV = mm32(Af, BIN1.v, ACCV);                                        \
    }

// C regs (gelu'd, register order == phi order) -> next-layer B fragments.
#define RELAYOUT(SRC, B0V, B1V)                                               \
    {                                                                         \
        B0V.u[0] = pack2(SRC[0],  SRC[1]);                                    \
        B0V.u[1] = pack2(SRC[2],  SRC[3]);                                    \
        B0V.u[2] = pack2(SRC[4],  SRC[5]);                                    \
        B0V.u[3] = pack2(SRC[6],  SRC[7]);                                    \
        B1V.u[0] = pack2(SRC[8],  SRC[9]);                                    \
        B1V.u[1] = pack2(SRC[10], SRC[11]);                                   \
        B1V.u[2] = pack2(SRC[12], SRC[13]);                                   \
        B1V.u[3] = pack2(SRC[14], SRC[15]);                                   \
    }

__global__ __launch_bounds__(256, 4) void main_kernel(
    const float* __restrict__ Pf, const float* __restrict__ Of,
    const int* __restrict__ args,
    const float* __restrict__ W1, const float* __restrict__ g1,
    const float* __restrict__ v1,
    const float* __restrict__ W2, const float* __restrict__ g2,
    const float* __restrict__ b2, const float* __restrict__ m2,
    const float* __restrict__ v2,
    const float* __restrict__ W3, const float* __restrict__ g3,
    const float* __restrict__ b3, const float* __restrict__ m3,
    const float* __restrict__ v3,
    const float* __restrict__ W4, const float* __restrict__ g4,
    const float* __restrict__ b4, const float* __restrict__ m4,
    const float* __restrict__ v4,
    const float* __restrict__ Wc, const float* __restrict__ bc,
    const float* __restrict__ ws, float* __restrict__ out)
{
    __shared__ __align__(16) unsigned wfrag[3][2][2][64][4]; // L,khalf,hi/lo,lane,pair
    __shared__ __align__(16) float btl[3 * 32];   // BN beta by [L][ch]
    __shared__ __align__(16) float wch[3 * 32];   // Wc rows A,B,O by ch
    __shared__ __align__(16) float w1t[2 * 32];   // W1 cols 65,66 folded, by ch
    __shared__ float bcs[3];
    __shared__ int   izs;

    const float* Ws[3] = {W2, W3, W4};
    const float* gs[3] = {g2, g3, g4};
    const float* vs[3] = {v2, v3, v4};
    const float* bs[3] = {b2, b3, b4};
    const float* ms[3] = {m2, m3, m4};

    for (int idx = threadIdx.x; idx < 1536; idx += 256) {
        int pp  = idx & 3;
        int ln  = (idx >> 2) & 63;
        int kh  = (idx >> 8) & 1;
        int L   = idx >> 9;
        int row = ln & 31;
        int g   = ln >> 5;
        // phi(g, e) = 4g + (e&3) + 8*(e>>2); pair pp covers elems 2pp, 2pp+1
        int k   = kh * 16 + 4 * g + 2 * (pp & 1) + 8 * (pp >> 1);
        float inv = gs[L][row] * rsqrtf(vs[L][row] + 1e-5f);
        float w0 = Ws[L][row * 32 + k]     * inv;
        float w1 = Ws[L][row * 32 + k + 1] * inv;
        unsigned hiw, low;
        split_pack(w0, w1, hiw, low);
        wfrag[L][kh][0][ln][pp] = hiw;
        wfrag[L][kh][1][ln][pp] = low;
    }
    if (threadIdx.x < 96) {
        int L = threadIdx.x >> 5, ch = threadIdx.x & 31;
        btl[threadIdx.x] = bs[L][ch] - ms[L][ch] * (gs[L][ch] * rsqrtf(vs[L][ch] + 1e-5f));
        wch[threadIdx.x] = Wc[L * 32 + ch];
    }
    if (threadIdx.x < 64) {
        int t = threadIdx.x >> 5, ch = threadIdx.x & 31;
        float i1 = g1[ch] * rsqrtf(v1[ch] + 1e-5f);
        w1t[threadIdx.x] = W1[ch * 67 + 65 + t] * i1;
    }
    if (threadIdx.x < 3) bcs[threadIdx.x] = bc[threadIdx.x];
    if (threadIdx.x == 0) izs = (int)(args[0] >> 16);   // == 0, opaque
    __syncthreads();

    const int lane  = threadIdx.x & 63;
    const int wid   = threadIdx.x >> 6;
    const int m     = lane & 15;          // m-index (softmax axis)
    const int pt    = (lane >> 4) & 1;    // which of the 2 points in the pass
    const int hi    = lane >> 5;          // k-group
    const int q4    = hi << 2;            // 4*hi
    const int izero = izs;                // 0, compiler-opaque

    const int base  = blockIdx.x * 32 + wid * 8 + pt;   // 4 iterations x stride 2

    // ---- pipeline carries (loaded for iter 0 here; refilled at each tail) --
    f4 y0, y1, y2, y3, z0, z1, z2, z3;
    float of0v, of1v, pfg_n;
    int   aI_n;
    {
        const int C0 = base;
        const int b0 = (C0 >= NN) ? 1 : 0;
        const int n0 = C0 - b0 * NN;
        const int a0 = args[(b0 * NUMM + m) * NN + n0];
        of0v = Of[((b0 * 2 + 0) * NUMM + m) * NN + n0];
        of1v = Of[((b0 * 2 + 1) * NUMM + m) * NN + n0];
        pfg_n = Pf[b0 * NN + a0];
        const f4* yb = (const f4*)(ws + (size_t)(b0 * NN + n0) * 32);
        const f4* zb = (const f4*)(ws + ZOFS + (size_t)(b0 * NN + a0) * 32);
        y0 = yb[hi]; y1 = yb[2 + hi]; y2 = yb[4 + hi]; y3 = yb[6 + hi];
        z0 = zb[hi]; z1 = zb[2 + hi]; z2 = zb[4 + hi]; z3 = zb[6 + hi];
        // args for iter 1
        const int C1 = (C0 + 2 < BB * NN) ? C0 + 2 : BB * NN - 1;
        const int b1_ = (C1 >= NN) ? 1 : 0;
        const int n1_ = C1 - b1_ * NN;
        aI_n = args[(b1_ * NUMM + m) * NN + n1_];
    }

#pragma unroll 1
    for (int i = 0; i < 4; i++) {
        const int io = i & izero;                         // 0 every iter, unprovable
        const int C  = base + i * 2;
        const int b  = (C >= NN) ? 1 : 0;
        const int n  = C - b * NN;
        const float pfg = pfg_n;                          // consumed in epilogue

        const f4 wa0 = *(const f4*)&w1t[q4 + 4 * io];
        const f4 wa1 = *(const f4*)&w1t[8 + q4 + 4 * io];
        const f4 wa2 = *(const f4*)&w1t[16 + q4 + 4 * io];
        const f4 wa3 = *(const f4*)&w1t[24 + q4 + 4 * io];
        const f4 wb0 = *(const f4*)&w1t[32 + q4 + 4 * io];
        const f4 wb1 = *(const f4*)&w1t[40 + q4 + 4 * io];
        const f4 wb2 = *(const f4*)&w1t[48 + q4 + 4 * io];
        const f4 wb3 = *(const f4*)&w1t[56 + q4 + 4 * io];

        // ---- layer 1: h1 = gelu(Y+Z+of terms) -> directly the B fragments ----
        float x[16];
#pragma unroll
        for (int j = 0; j < 4; j++) {
            x[j]      = fmaf(of1v, wb0[j], fmaf(of0v, wa0[j], y0[j] + z0[j]));
            x[4 + j]  = fmaf(of1v, wb1[j], fmaf(of0v, wa1[j], y1[j] + z1[j]));
            x[8 + j]  = fmaf(of1v, wb2[j], fmaf(of0v, wa2[j], y2[j] + z2[j]));
            x[12 + j] = fmaf(of1v, wb3[j], fmaf(of0v, wa3[j], y3[j] + z3[j]));
        }
#pragma unroll
        for (int j = 0; j < 16; j++) x[j] = gelu_fast(x[j]);
        UV B0, B1;
        RELAYOUT(x, B0, B1);

        // next-point coordinates (clamped; wasted loads on last iter)
        const int Cn = (C + 2 < BB * NN) ? C + 2 : BB * NN - 1;
        const int bn = (Cn >= NN) ? 1 : 0;
        const int nn = Cn - bn * NN;

        // ---- layer 2 ----
        f16v acc;
        LAYER(0, B0, B1, acc);
        float h2g[16];
#pragma unroll
        for (int r = 0; r < 16; r++) h2g[r] = gelu_fast(acc[r]);
        RELAYOUT(h2g, B0, B1);

        // prefetch y/of for next iter (y regs died at L1; live-range reuse)
        {
            const f4* ybn = (const f4*)(ws + (size_t)(bn * NN + nn) * 32);
            y0 = ybn[hi]; y1 = ybn[2 + hi]; y2 = ybn[4 + hi]; y3 = ybn[6 + hi];
            of0v = Of[((bn * 2 + 0) * NUMM + m) * NN + nn];
            of1v = Of[((bn * 2 + 1) * NUMM + m) * NN + nn];
        }

        // ---- layer 3 ----
        LAYER(1, B0, B1, acc);
        float h3g[16];
#pragma unroll
        for (int r = 0; r < 16; r++) h3g[r] = gelu_fast(acc[r]);
        RELAYOUT(h3g, B0, B1);

        // prefetch z/pf for next iter (args_next landed ~2 layers ago),
        // then issue args for iter i+2 into the freed carry.
        {
            const int aN = aI_n;
            pfg_n = Pf[bn * NN + aN];
            const f4* zbn = (const f4*)(ws + ZOFS + (size_t)(bn * NN + aN) * 32);
            z0 = zbn[hi]; z1 = zbn[2 + hi]; z2 = zbn[4 + hi]; z3 = zbn[6 + hi];
            const int Ca = (C + 4 < BB * NN) ? C + 4 : BB * NN - 1;
            const int ba = (Ca >= NN) ? 1 : 0;
            const int na = Ca - ba * NN;
            aI_n = args[(ba * NUMM + m) * NN + na];
        }

        // ---- layer 4 + residual + head (all in C layout) ----
        LAYER(2, B0, B1, acc);

        float pa = 0.0f, pb = 0.0f, po = 0.0f;
#pragma unroll
        for (int q = 0; q < 4; q++) {
            const f4 wAq = *(const f4*)&wch[      8 * q + q4 + 4 * io];
            const f4 wBq = *(const f4*)&wch[32 +  8 * q + q4 + 4 * io];
            const f4 wOq = *(const f4*)&wch[64 +  8 * q + q4 + 4 * io];
#pragma unroll
            for (int r2 = 0; r2 < 4; r2++) {
                float xf = gelu_fast(h2g[4 * q + r2] + acc[4 * q + r2]);
                pa = fmaf(wAq[r2], xf, pa);
                pb = fmaf(wBq[r2], xf, pb);
                po = fmaf(wOq[r2], xf, po);
            }
        }
        // partner half (lane^32) holds the other 16 channels
        pa += __shfl_xor(pa, 32, 64);
        pb += __shfl_xor(pb, 32, 64);
        po += __shfl_xor(po, 32, 64);

        const float alpha = pa + bcs[0];
        const float beta_ = pb + bcs[1];
        const float omega = po + bcs[2];
        const float val = fmaf(alpha + 1.0f, pfg, beta_);

        // softmax over the 16 m's (within each 16-lane group)
        float mx = omega;
#pragma unroll
        for (int s = 1; s < 16; s <<= 1) mx = fmaxf(mx, __shfl_xor(mx, s, 64));
        const float e = __expf(omega - mx);
        float S = e, T = val * e;
#pragma unroll
        for (int s = 1; s < 16; s <<= 1) {
            S += __shfl_xor(S, s, 64);
            T += __shfl_xor(T, s, 64);
        }
        if ((lane & 15) == 0 && lane < 32)
            out[b * NN + n] = T * __builtin_amdgcn_rcpf(S);
    }
}

// ---- launcher ---------------------------------------------------------------
extern "C" void kernel_launch(void* const* d_in, const int* in_sizes, int n_in,
                              void* d_out, int out_size, void* d_ws, size_t ws_size,
                              hipStream_t stream) {
    const float* If    = (const float*)d_in[0];
    const float* Pf    = (const float*)d_in[1];
    const float* Of    = (const float*)d_in[2];
    const int*   args  = (const int*)d_in[3];
    const float* W1    = (const float*)d_in[4];
    const float* g1    = (const float*)d_in[5];
    const float* b1    = (const float*)d_in[6];
    const float* m1    = (const float*)d_in[7];
    const float* v1    = (const float*)d_in[8];
    const float* W2    = (const float*)d_in[9];
    const float* g2    = (const float*)d_in[10];
    const float* b2    = (const float*)d_in[11];
    const float* m2    = (const float*)d_in[12];
    const float* v2    = (const float*)d_in[13];
    const float* W3    = (const float*)d_in[14];
    const float* g3    = (const float*)d_in[15];
    const float* b3    = (const float*)d_in[16];
    const float* m3    = (const float*)d_in[17];
    const float* v3    = (const float*)d_in[18];
    const float* W4    = (const float*)d_in[19];
    const float* g4    = (const float*)d_in[20];
    const float* b4    = (const float*)d_in[21];
    const float* m4    = (const float*)d_in[22];
    const float* v4    = (const float*)d_in[23];
    const float* Wc    = (const float*)d_in[24];
    const float* bc    = (const float*)d_in[25];

    float* ws  = (float*)d_ws;
    float* out = (float*)d_out;

    yz_kernel<<<(BB * NN) / 64, 256, 0, stream>>>(
        If, Pf, W1, g1, b1, m1, v1, ws);

    main_kernel<<<(BB * NN) / 32, 256, 0, stream>>>(
        Pf, Of, args,
        W1, g1, v1,
        W2, g2, b2, m2, v2,
        W3, g3, b3, m3, v3,
        W4, g4, b4, m4, v4,
        Wc, bc, ws, out);
}

// Round 5
// 226.796 us; speedup vs baseline: 1.0269x; 1.0024x over previous
//
#include <hip/hip_runtime.h>
#include <math.h>

#define BB   2
#define CFI  32
#define NN   36864          // 192*192
#define NUMM 16

// workspace: Y at ws[0..], Z at ws[ZOFS..]  (point-major [B*N][32] each)
#define ZOFS (BB * NN * CFI)

typedef __attribute__((ext_vector_type(8))) short short8;   // 8 bf16 (4 VGPRs)
typedef __attribute__((ext_vector_type(4))) float f4;       // 4 f32
typedef __attribute__((ext_vector_type(16))) float f16v;    // 16 f32 (32x32 acc)

static __device__ __forceinline__ f16v mm32(short8 a, short8 b, f16v c) {
    return __builtin_amdgcn_mfma_f32_32x32x16_bf16(a, b, c, 0, 0, 0);
}

// DPP-based 16-lane-row reductions (VALU latency, no LDS pipe).
// 0xB1 = quad_perm [1,0,3,2] (xor1), 0x4E = quad_perm [2,3,0,1] (xor2),
// 0x141 = row_half_mirror (8-lane), 0x140 = row_mirror (16-lane).
template <int CTRL>
static __device__ __forceinline__ float dpp_add(float x) {
    int y = __builtin_amdgcn_update_dpp(0, __builtin_bit_cast(int, x),
                                        CTRL, 0xf, 0xf, true);
    return x + __builtin_bit_cast(float, y);
}
template <int CTRL>
static __device__ __forceinline__ float dpp_max(float x) {
    int y = __builtin_amdgcn_update_dpp(0, __builtin_bit_cast(int, x),
                                        CTRL, 0xf, 0xf, true);
    return fmaxf(x, __builtin_bit_cast(float, y));
}

// tanh-form gelu: x * sigmoid(1.595769x + 0.0713548x^3), exp2-folded.
static __device__ __forceinline__ float gelu_fast(float x) {
    const float x2  = x * x;
    const float q   = fmaf(-0.10294310f, x2, -2.30211813f);
    const float e   = exp2f(q * x);
    const float r   = __builtin_amdgcn_rcpf(e + 1.0f);
    return x * r;
}

static __device__ __forceinline__ unsigned bf16_rne_bits(float x) {
    unsigned u = __builtin_bit_cast(unsigned, x);
    return u + 0x7fffu + ((u >> 16) & 1u);
}
static __device__ __forceinline__ void split_pack(float x0, float x1,
                                                  unsigned& hi, unsigned& lo) {
    unsigned r0 = bf16_rne_bits(x0);
    unsigned r1 = bf16_rne_bits(x1);
    float h0 = __builtin_bit_cast(float, r0 & 0xffff0000u);
    float h1 = __builtin_bit_cast(float, r1 & 0xffff0000u);
    hi = (r0 >> 16) | (r1 & 0xffff0000u);
    unsigned s0 = bf16_rne_bits(x0 - h0);
    unsigned s1 = bf16_rne_bits(x1 - h1);
    lo = (s0 >> 16) | (s1 & 0xffff0000u);
}

// cheap round-half-up bf16 pair pack (activations)
static __device__ __forceinline__ unsigned pack2(float a, float b) {
    unsigned ua = __builtin_bit_cast(unsigned, a) + 0x8000u;
    unsigned ub = __builtin_bit_cast(unsigned, b) + 0x8000u;
    return (ua >> 16) | (ub & 0xffff0000u);
}

union UV { unsigned u[4]; short8 v; };

// ---- kernel A: per-point Y/Z precompute (layer-1 split) -- unchanged ------
__global__ __launch_bounds__(256) void yz_kernel(
    const float* __restrict__ If, const float* __restrict__ Pf,
    const float* __restrict__ W1, const float* __restrict__ g1,
    const float* __restrict__ b1, const float* __restrict__ m1,
    const float* __restrict__ v1,
    float* __restrict__ wsYZ)
{
    __shared__ float wy[1024], wz[1024], wp[32], bt1[32];
    for (int i = threadIdx.x; i < 1024; i += 256) {
        int o = i >> 5, c = i & 31;
        float inv = g1[o] * rsqrtf(v1[o] + 1e-5f);
        wy[i] = W1[o * 67 + c]      * inv;
        wz[i] = W1[o * 67 + 32 + c] * inv;
    }
    if (threadIdx.x < 32) {
        int o = threadIdx.x;
        float inv = g1[o] * rsqrtf(v1[o] + 1e-5f);
        wp[o]  = W1[o * 67 + 64] * inv;
        bt1[o] = b1[o] - m1[o] * inv;
    }
    __syncthreads();

    const int r  = threadIdx.x & 3;
    const int p  = blockIdx.x * 64 + (threadIdx.x >> 2);
    const int b  = p / NN, n = p - b * NN;
    const int o0 = r * 8;
    const float* ifp = If + (size_t)b * CFI * NN + n;

    float v[32];
#pragma unroll
    for (int c = 0; c < 32; c++) v[c] = ifp[(size_t)c * NN];
    const float pf = Pf[p];

    float accY[8], accZ[8];
#pragma unroll
    for (int j = 0; j < 8; j++) {
        const float4* wyr = (const float4*)&wy[(o0 + j) * 32];
        const float4* wzr = (const float4*)&wz[(o0 + j) * 32];
        float ay = bt1[o0 + j];
        float az = wp[o0 + j] * pf;
#pragma unroll
        for (int c4 = 0; c4 < 8; c4++) {
            float4 a = wyr[c4], z = wzr[c4];
            ay = fmaf(a.x, v[4 * c4 + 0], ay);  az = fmaf(z.x, v[4 * c4 + 0], az);
            ay = fmaf(a.y, v[4 * c4 + 1], ay);  az = fmaf(z.y, v[4 * c4 + 1], az);
            ay = fmaf(a.z, v[4 * c4 + 2], ay);  az = fmaf(z.z, v[4 * c4 + 2], az);
            ay = fmaf(a.w, v[4 * c4 + 3], ay);  az = fmaf(z.w, v[4 * c4 + 3], az);
        }
        accY[j] = ay; accZ[j] = az;
    }

    float4* yp = (float4*)(wsYZ + (size_t)p * 32 + o0);
    float4* zp = (float4*)(wsYZ + ZOFS + (size_t)p * 32 + o0);
    yp[0] = make_float4(accY[0], accY[1], accY[2], accY[3]);
    yp[1] = make_float4(accY[4], accY[5], accY[6], accY[7]);
    zp[0] = make_float4(accZ[0], accZ[1], accZ[2], accZ[3]);
    zp[1] = make_float4(accZ[4], accZ[5], accZ[6], accZ[7]);
}

// ---- kernel B: 32x32x16 MFMA MLP, 2 pts/pass, gather pipeline, DPP tail ---
// r15: phi(g,j) k-relabeling -> relayout = 8 pack2, zero cross-lane ops.
// r16: (256,4) killed the spill; dur unchanged -> latency-bound.
// r17: 4-deep gather pipeline: -6% (103->97). Remaining exposed latency:
//      (a) softmax tail = ~12 serially-dependent ds_swizzle shfls
//          (~600-1000cy on the LDS pipe), (b) per-layer wfrag/bias LDS
//          reads stalling the first MFMA (~120cy each layer head).
// r18: (a) DPP reductions for the 16-lane max/S/T trees (VALU latency,
//      rows align with m-groups); only 3 parallel shfl_xor(32) remain on
//      LDS. (b) LOADL(L): layer frag+bias reads issued right after the
//      previous layer's MFMAs, covered by the 16-gelu block.
#define LOADL(Lc)                                                             \
    {                                                                         \
        A0l = *(const short8*)&wfrag[(Lc)][0][1][lane + io][0];               \
        A0h = *(const short8*)&wfrag[(Lc)][0][0][lane + io][0];               \
        A1l = *(const short8*)&wfrag[(Lc)][1][1][lane + io][0];               \
        A1h = *(const short8*)&wfrag[(Lc)][1][0][lane + io][0];               \
        bq0 = *(const f4*)&btl[(Lc) * 32 +      4 * hi + 4 * io];             \
        bq1 = *(const f4*)&btl[(Lc) * 32 +  8 + 4 * hi + 4 * io];             \
        bq2 = *(const f4*)&btl[(Lc) * 32 + 16 + 4 * hi + 4 * io];             \
        bq3 = *(const f4*)&btl[(Lc) * 32 + 24 + 4 * hi + 4 * io];             \
    }

#define LAYER_MM(ACCV, BIN0, BIN1)                                            \
    {                                                                         \
        ACCV[0]  = bq0[0]; ACCV[1]  = bq0[1]; ACCV[2]  = bq0[2]; ACCV[3]  = bq0[3]; \
        ACCV[4]  = bq1[0]; ACCV[5]  = bq1[1]; ACCV[6]  = bq1[2]; ACCV[7]  = bq1[3]; \
        ACCV[8]  = bq2[0]; ACCV[9]  = bq2[1]; ACCV[10] = bq2[2]; ACCV[11] = bq2[3]; \
        ACCV[12] = bq3[0]; ACCV[13] = bq3[1]; ACCV[14] = bq3[2]; ACCV[15] = bq3[3]; \
        ACCV = mm32(A0l, BIN0.v, ACCV);                                       \
        ACCV = mm32(A0h, BIN0.v, ACCV);                                       \
        ACCV = mm32(A1l, BIN1.v, ACCV);                                       \
        ACCV = mm32(A1h, BIN1.v, ACCV);                                       \
    }

// C regs (gelu'd, register order == phi order) -> next-layer B fragments.
#define RELAYOUT(SRC, B0V, B1V)                                               \
    {                                                                         \
        B0V.u[0] = pack2(SRC[0],  SRC[1]);                                    \
        B0V.u[1] = pack2(SRC[2],  SRC[3]);                                    \
        B0V.u[2] = pack2(SRC[4],  SRC[5]);                                    \
        B0V.u[3] = pack2(SRC[6],  SRC[7]);                                    \
        B1V.u[0] = pack2(SRC[8],  SRC[9]);                                    \
        B1V.u[1] = pack2(SRC[10], SRC[11]);                                   \
        B1V.u[2] = pack2(SRC[12], SRC[13]);                                   \
        B1V.u[3] = pack2(SRC[14], SRC[15]);                                   \
    }

__global__ __launch_bounds__(256, 4) void main_kernel(
    const float* __restrict__ Pf, const float* __restrict__ Of,
    const int* __restrict__ args,
    const float* __restrict__ W1, const float* __restrict__ g1,
    const float* __restrict__ v1,
    const float* __restrict__ W2, const float* __restrict__ g2,
    const float* __restrict__ b2, const float* __restrict__ m2,
    const float* __restrict__ v2,
    const float* __restrict__ W3, const float* __restrict__ g3,
    const float* __restrict__ b3, const float* __restrict__ m3,
    const float* __restrict__ v3,
    const float* __restrict__ W4, const float* __restrict__ g4,
    const float* __restrict__ b4, const float* __restrict__ m4,
    const float* __restrict__ v4,
    const float* __restrict__ Wc, const float* __restrict__ bc,
    const float* __restrict__ ws, float* __restrict__ out)
{
    __shared__ __align__(16) unsigned wfrag[3][2][2][64][4]; // L,khalf,hi/lo,lane,pair
    __shared__ __align__(16) float btl[3 * 32];   // BN beta by [L][ch]
    __shared__ __align__(16) float wch[3 * 32];   // Wc rows A,B,O by ch
    __shared__ __align__(16) float w1t[2 * 32];   // W1 cols 65,66 folded, by ch
    __shared__ float bcs[3];
    __shared__ int   izs;

    const float* Ws[3] = {W2, W3, W4};
    const float* gs[3] = {g2, g3, g4};
    const float* vs[3] = {v2, v3, v4};
    const float* bs[3] = {b2, b3, b4};
    const float* ms[3] = {m2, m3, m4};

    for (int idx = threadIdx.x; idx < 1536; idx += 256) {
        int pp  = idx & 3;
        int ln  = (idx >> 2) & 63;
        int kh  = (idx >> 8) & 1;
        int L   = idx >> 9;
        int row = ln & 31;
        int g   = ln >> 5;
        // phi(g, e) = 4g + (e&3) + 8*(e>>2); pair pp covers elems 2pp, 2pp+1
        int k   = kh * 16 + 4 * g + 2 * (pp & 1) + 8 * (pp >> 1);
        float inv = gs[L][row] * rsqrtf(vs[L][row] + 1e-5f);
        float w0 = Ws[L][row * 32 + k]     * inv;
        float w1 = Ws[L][row * 32 + k + 1] * inv;
        unsigned hiw, low;
        split_pack(w0, w1, hiw, low);
        wfrag[L][kh][0][ln][pp] = hiw;
        wfrag[L][kh][1][ln][pp] = low;
    }
    if (threadIdx.x < 96) {
        int L = threadIdx.x >> 5, ch = threadIdx.x & 31;
        btl[threadIdx.x] = bs[L][ch] - ms[L][ch] * (gs[L][ch] * rsqrtf(vs[L][ch] + 1e-5f));
        wch[threadIdx.x] = Wc[L * 32 + ch];
    }
    if (threadIdx.x < 64) {
        int t = threadIdx.x >> 5, ch = threadIdx.x & 31;
        float i1 = g1[ch] * rsqrtf(v1[ch] + 1e-5f);
        w1t[threadIdx.x] = W1[ch * 67 + 65 + t] * i1;
    }
    if (threadIdx.x < 3) bcs[threadIdx.x] = bc[threadIdx.x];
    if (threadIdx.x == 0) izs = (int)(args[0] >> 16);   // == 0, opaque
    __syncthreads();

    const int lane  = threadIdx.x & 63;
    const int wid   = threadIdx.x >> 6;
    const int m     = lane & 15;          // m-index (softmax axis)
    const int pt    = (lane >> 4) & 1;    // which of the 2 points in the pass
    const int hi    = lane >> 5;          // k-group
    const int q4    = hi << 2;            // 4*hi
    const int izero = izs;                // 0, compiler-opaque

    const int base  = blockIdx.x * 32 + wid * 8 + pt;   // 4 iterations x stride 2

    // ---- pipeline carries (loaded for iter 0 here; refilled at each tail) --
    f4 y0, y1, y2, y3, z0, z1, z2, z3;
    float of0v, of1v, pfg_n;
    int   aI_n;
    {
        const int C0 = base;
        const int b0 = (C0 >= NN) ? 1 : 0;
        const int n0 = C0 - b0 * NN;
        const int a0 = args[(b0 * NUMM + m) * NN + n0];
        of0v = Of[((b0 * 2 + 0) * NUMM + m) * NN + n0];
        of1v = Of[((b0 * 2 + 1) * NUMM + m) * NN + n0];
        pfg_n = Pf[b0 * NN + a0];
        const f4* yb = (const f4*)(ws + (size_t)(b0 * NN + n0) * 32);
        const f4* zb = (const f4*)(ws + ZOFS + (size_t)(b0 * NN + a0) * 32);
        y0 = yb[hi]; y1 = yb[2 + hi]; y2 = yb[4 + hi]; y3 = yb[6 + hi];
        z0 = zb[hi]; z1 = zb[2 + hi]; z2 = zb[4 + hi]; z3 = zb[6 + hi];
        // args for iter 1
        const int C1 = (C0 + 2 < BB * NN) ? C0 + 2 : BB * NN - 1;
        const int b1_ = (C1 >= NN) ? 1 : 0;
        const int n1_ = C1 - b1_ * NN;
        aI_n = args[(b1_ * NUMM + m) * NN + n1_];
    }

#pragma unroll 1
    for (int i = 0; i < 4; i++) {
        const int io = i & izero;                         // 0 every iter, unprovable
        const int C  = base + i * 2;
        const int b  = (C >= NN) ? 1 : 0;
        const int n  = C - b * NN;
        const float pfg = pfg_n;                          // consumed in epilogue

        short8 A0l, A0h, A1l, A1h;
        f4 bq0, bq1, bq2, bq3;
        LOADL(0);                                         // covered by L1 math

        const f4 wa0 = *(const f4*)&w1t[q4 + 4 * io];
        const f4 wa1 = *(const f4*)&w1t[8 + q4 + 4 * io];
        const f4 wa2 = *(const f4*)&w1t[16 + q4 + 4 * io];
        const f4 wa3 = *(const f4*)&w1t[24 + q4 + 4 * io];
        const f4 wb0 = *(const f4*)&w1t[32 + q4 + 4 * io];
        const f4 wb1 = *(const f4*)&w1t[40 + q4 + 4 * io];
        const f4 wb2 = *(const f4*)&w1t[48 + q4 + 4 * io];
        const f4 wb3 = *(const f4*)&w1t[56 + q4 + 4 * io];

        // ---- layer 1: h1 = gelu(Y+Z+of terms) -> directly the B fragments ----
        float x[16];
#pragma unroll
        for (int j = 0; j < 4; j++) {
            x[j]      = fmaf(of1v, wb0[j], fmaf(of0v, wa0[j], y0[j] + z0[j]));
            x[4 + j]  = fmaf(of1v, wb1[j], fmaf(of0v, wa1[j], y1[j] + z1[j]));
            x[8 + j]  = fmaf(of1v, wb2[j], fmaf(of0v, wa2[j], y2[j] + z2[j]));
            x[12 + j] = fmaf(of1v, wb3[j], fmaf(of0v, wa3[j], y3[j] + z3[j]));
        }
#pragma unroll
        for (int j = 0; j < 16; j++) x[j] = gelu_fast(x[j]);
        UV B0, B1;
        RELAYOUT(x, B0, B1);

        // next-point coordinates (clamped; wasted loads on last iter)
        const int Cn = (C + 2 < BB * NN) ? C + 2 : BB * NN - 1;
        const int bn = (Cn >= NN) ? 1 : 0;
        const int nn = Cn - bn * NN;

        // ---- layer 2 ----
        f16v acc;
        LAYER_MM(acc, B0, B1);
        LOADL(1);                                         // covered by gelu(h2)
        float h2g[16];
#pragma unroll
        for (int r = 0; r < 16; r++) h2g[r] = gelu_fast(acc[r]);
        RELAYOUT(h2g, B0, B1);

        // prefetch y/of for next iter (y regs died at L1; live-range reuse)
        {
            const f4* ybn = (const f4*)(ws + (size_t)(bn * NN + nn) * 32);
            y0 = ybn[hi]; y1 = ybn[2 + hi]; y2 = ybn[4 + hi]; y3 = ybn[6 + hi];
            of0v = Of[((bn * 2 + 0) * NUMM + m) * NN + nn];
            of1v = Of[((bn * 2 + 1) * NUMM + m) * NN + nn];
        }

        // ---- layer 3 ----
        LAYER_MM(acc, B0, B1);
        LOADL(2);                                         // covered by gelu(h3)
        float h3g[16];
#pragma unroll
        for (int r = 0; r < 16; r++) h3g[r] = gelu_fast(acc[r]);
        RELAYOUT(h3g, B0, B1);

        // prefetch z/pf for next iter (args_next landed ~2 layers ago),
        // then issue args for iter i+2 into the freed carry.
        {
            const int aN = aI_n;
            pfg_n = Pf[bn * NN + aN];
            const f4* zbn = (const f4*)(ws + ZOFS + (size_t)(bn * NN + aN) * 32);
            z0 = zbn[hi]; z1 = zbn[2 + hi]; z2 = zbn[4 + hi]; z3 = zbn[6 + hi];
            const int Ca = (C + 4 < BB * NN) ? C + 4 : BB * NN - 1;
            const int ba = (Ca >= NN) ? 1 : 0;
            const int na = Ca - ba * NN;
            aI_n = args[(ba * NUMM + m) * NN + na];
        }

        // ---- layer 4 + residual + head (all in C layout) ----
        LAYER_MM(acc, B0, B1);

        float pa = 0.0f, pb = 0.0f, po = 0.0f;
#pragma unroll
        for (int q = 0; q < 4; q++) {
            const f4 wAq = *(const f4*)&wch[      8 * q + q4 + 4 * io];
            const f4 wBq = *(const f4*)&wch[32 +  8 * q + q4 + 4 * io];
            const f4 wOq = *(const f4*)&wch[64 +  8 * q + q4 + 4 * io];
#pragma unroll
            for (int r2 = 0; r2 < 4; r2++) {
                float xf = gelu_fast(h2g[4 * q + r2] + acc[4 * q + r2]);
                pa = fmaf(wAq[r2], xf, pa);
                pb = fmaf(wBq[r2], xf, pb);
                po = fmaf(wOq[r2], xf, po);
            }
        }
        // partner half (lane^32) holds the other 16 channels (LDS pipe, 3 parallel)
        pa += __shfl_xor(pa, 32, 64);
        pb += __shfl_xor(pb, 32, 64);
        po += __shfl_xor(po, 32, 64);

        const float alpha = pa + bcs[0];
        const float beta_ = pb + bcs[1];
        const float omega = po + bcs[2];
        const float val = fmaf(alpha + 1.0f, pfg, beta_);

        // softmax over the 16 m's — DPP row reductions (VALU latency)
        float mx = dpp_max<0xB1>(omega);
        mx = dpp_max<0x4E>(mx);
        mx = dpp_max<0x141>(mx);
        mx = dpp_max<0x140>(mx);
        const float e = __expf(omega - mx);
        float S = e, T = val * e;
        S = dpp_add<0xB1>(S);   T = dpp_add<0xB1>(T);
        S = dpp_add<0x4E>(S);   T = dpp_add<0x4E>(T);
        S = dpp_add<0x141>(S);  T = dpp_add<0x141>(T);
        S = dpp_add<0x140>(S);  T = dpp_add<0x140>(T);

        if ((lane & 15) == 0 && lane < 32)
            out[b * NN + n] = T * __builtin_amdgcn_rcpf(S);
    }
}

// ---- launcher ---------------------------------------------------------------
extern "C" void kernel_launch(void* const* d_in, const int* in_sizes, int n_in,
                              void* d_out, int out_size, void* d_ws, size_t ws_size,
                              hipStream_t stream) {
    const float* If    = (const float*)d_in[0];
    const float* Pf    = (const float*)d_in[1];
    const float* Of    = (const float*)d_in[2];
    const int*   args  = (const int*)d_in[3];
    const float* W1    = (const float*)d_in[4];
    const float* g1    = (const float*)d_in[5];
    const float* b1    = (const float*)d_in[6];
    const float* m1    = (const float*)d_in[7];
    const float* v1    = (const float*)d_in[8];
    const float* W2    = (const float*)d_in[9];
    const float* g2    = (const float*)d_in[10];
    const float* b2    = (const float*)d_in[11];
    const float* m2    = (const float*)d_in[12];
    const float* v2    = (const float*)d_in[13];
    const float* W3    = (const float*)d_in[14];
    const float* g3    = (const float*)d_in[15];
    const float* b3    = (const float*)d_in[16];
    const float* m3    = (const float*)d_in[17];
    const float* v3    = (const float*)d_in[18];
    const float* W4    = (const float*)d_in[19];
    const float* g4    = (const float*)d_in[20];
    const float* b4    = (const float*)d_in[21];
    const float* m4    = (const float*)d_in[22];
    const float* v4    = (const float*)d_in[23];
    const float* Wc    = (const float*)d_in[24];
    const float* bc    = (const float*)d_in[25];

    float* ws  = (float*)d_ws;
    float* out = (float*)d_out;

    yz_kernel<<<(BB * NN) / 64, 256, 0, stream>>>(
        If, Pf, W1, g1, b1, m1, v1, ws);

    main_kernel<<<(BB * NN) / 32, 256, 0, stream>>>(
        Pf, Of, args,
        W1, g1, v1,
        W2, g2, b2, m2, v2,
        W3, g3, b3, m3, v3,
        W4, g4, b4, m4, v4,
        Wc, bc, ws, out);
}

// Round 7
// 226.696 us; speedup vs baseline: 1.0273x; 1.0004x over previous
//
#include <hip/hip_runtime.h>
#include <math.h>

#define BB   2
#define CFI  32
#define NN   36864          // 192*192
#define NUMM 16

// workspace (packed bf16 pairs): Y at wsu[0..], Z at wsu[ZOFSU..]
// per point: 16 u32 = 32 channels. u32 idx = hi*8 + q*2 + pair,
// channel c = 8q + 4hi + 2pair + {lo,hi16}.
#define ZOFSU (BB * NN * 16)

typedef __attribute__((ext_vector_type(8))) short short8;   // 8 bf16 (4 VGPRs)
typedef __attribute__((ext_vector_type(4))) float f4;       // 4 f32
typedef __attribute__((ext_vector_type(16))) float f16v;    // 16 f32 (32x32 acc)
typedef __attribute__((ext_vector_type(4))) unsigned uint4v;
typedef __attribute__((ext_vector_type(2))) unsigned u2v;

static __device__ __forceinline__ f16v mm32(short8 a, short8 b, f16v c) {
    return __builtin_amdgcn_mfma_f32_32x32x16_bf16(a, b, c, 0, 0, 0);
}

// DPP-based 16-lane-row reductions (VALU latency, no LDS pipe).
template <int CTRL>
static __device__ __forceinline__ float dpp_add(float x) {
    int y = __builtin_amdgcn_update_dpp(0, __builtin_bit_cast(int, x),
                                        CTRL, 0xf, 0xf, true);
    return x + __builtin_bit_cast(float, y);
}
template <int CTRL>
static __device__ __forceinline__ float dpp_max(float x) {
    int y = __builtin_amdgcn_update_dpp(0, __builtin_bit_cast(int, x),
                                        CTRL, 0xf, 0xf, true);
    return fmaxf(x, __builtin_bit_cast(float, y));
}

// tanh-form gelu: x * sigmoid(1.595769x + 0.0713548x^3), exp2-folded.
static __device__ __forceinline__ float gelu_fast(float x) {
    const float x2  = x * x;
    const float q   = fmaf(-0.10294310f, x2, -2.30211813f);
    const float e   = exp2f(q * x);
    const float r   = __builtin_amdgcn_rcpf(e + 1.0f);
    return x * r;
}

static __device__ __forceinline__ unsigned bf16_rne_bits(float x) {
    unsigned u = __builtin_bit_cast(unsigned, x);
    return u + 0x7fffu + ((u >> 16) & 1u);
}
static __device__ __forceinline__ void split_pack(float x0, float x1,
                                                  unsigned& hi, unsigned& lo) {
    unsigned r0 = bf16_rne_bits(x0);
    unsigned r1 = bf16_rne_bits(x1);
    float h0 = __builtin_bit_cast(float, r0 & 0xffff0000u);
    float h1 = __builtin_bit_cast(float, r1 & 0xffff0000u);
    hi = (r0 >> 16) | (r1 & 0xffff0000u);
    unsigned s0 = bf16_rne_bits(x0 - h0);
    unsigned s1 = bf16_rne_bits(x1 - h1);
    lo = (s0 >> 16) | (s1 & 0xffff0000u);
}

// cheap round-half-up bf16 pair pack (activations / workspace)
static __device__ __forceinline__ unsigned pack2(float a, float b) {
    unsigned ua = __builtin_bit_cast(unsigned, a) + 0x8000u;
    unsigned ub = __builtin_bit_cast(unsigned, b) + 0x8000u;
    return (ua >> 16) | (ub & 0xffff0000u);
}
static __device__ __forceinline__ float bflo(unsigned u) {
    return __builtin_bit_cast(float, u << 16);
}
static __device__ __forceinline__ float bfhi(unsigned u) {
    return __builtin_bit_cast(float, u & 0xffff0000u);
}

union UV { unsigned u[4]; short8 v; };

// ---- kernel A: per-point Y/Z precompute, packed-bf16 output ---------------
__global__ __launch_bounds__(256) void yz_kernel(
    const float* __restrict__ If, const float* __restrict__ Pf,
    const float* __restrict__ W1, const float* __restrict__ g1,
    const float* __restrict__ b1, const float* __restrict__ m1,
    const float* __restrict__ v1,
    float* __restrict__ wsYZ)
{
    __shared__ float wy[1024], wz[1024], wp[32], bt1[32];
    for (int i = threadIdx.x; i < 1024; i += 256) {
        int o = i >> 5, c = i & 31;
        float inv = g1[o] * rsqrtf(v1[o] + 1e-5f);
        wy[i] = W1[o * 67 + c]      * inv;
        wz[i] = W1[o * 67 + 32 + c] * inv;
    }
    if (threadIdx.x < 32) {
        int o = threadIdx.x;
        float inv = g1[o] * rsqrtf(v1[o] + 1e-5f);
        wp[o]  = W1[o * 67 + 64] * inv;
        bt1[o] = b1[o] - m1[o] * inv;
    }
    __syncthreads();

    const int r  = threadIdx.x & 3;
    const int p  = blockIdx.x * 64 + (threadIdx.x >> 2);
    const int b  = p / NN, n = p - b * NN;
    const int o0 = r * 8;
    const float* ifp = If + (size_t)b * CFI * NN + n;

    float v[32];
#pragma unroll
    for (int c = 0; c < 32; c++) v[c] = ifp[(size_t)c * NN];
    const float pf = Pf[p];

    float accY[8], accZ[8];
#pragma unroll
    for (int j = 0; j < 8; j++) {
        const float4* wyr = (const float4*)&wy[(o0 + j) * 32];
        const float4* wzr = (const float4*)&wz[(o0 + j) * 32];
        float ay = bt1[o0 + j];
        float az = wp[o0 + j] * pf;
#pragma unroll
        for (int c4 = 0; c4 < 8; c4++) {
            float4 a = wyr[c4], z = wzr[c4];
            ay = fmaf(a.x, v[4 * c4 + 0], ay);  az = fmaf(z.x, v[4 * c4 + 0], az);
            ay = fmaf(a.y, v[4 * c4 + 1], ay);  az = fmaf(z.y, v[4 * c4 + 1], az);
            ay = fmaf(a.z, v[4 * c4 + 2], ay);  az = fmaf(z.z, v[4 * c4 + 2], az);
            ay = fmaf(a.w, v[4 * c4 + 3], ay);  az = fmaf(z.w, v[4 * c4 + 3], az);
        }
        accY[j] = ay; accZ[j] = az;
    }

    // pack to bf16 pairs. thread r owns channels c = 8r + j (q == r):
    // j=0..3 -> hi=0 (u32 idx 2r, 2r+1), j=4..7 -> hi=1 (idx 8+2r, 8+2r+1).
    unsigned* wsu = (unsigned*)wsYZ;
    u2v yA, yB, zA, zB;
    yA[0] = pack2(accY[0], accY[1]); yA[1] = pack2(accY[2], accY[3]);
    yB[0] = pack2(accY[4], accY[5]); yB[1] = pack2(accY[6], accY[7]);
    zA[0] = pack2(accZ[0], accZ[1]); zA[1] = pack2(accZ[2], accZ[3]);
    zB[0] = pack2(accZ[4], accZ[5]); zB[1] = pack2(accZ[6], accZ[7]);
    *(u2v*)(wsu + (size_t)p * 16 + 2 * r)          = yA;
    *(u2v*)(wsu + (size_t)p * 16 + 8 + 2 * r)      = yB;
    *(u2v*)(wsu + ZOFSU + (size_t)p * 16 + 2 * r)     = zA;
    *(u2v*)(wsu + ZOFSU + (size_t)p * 16 + 8 + 2 * r) = zB;
}

// ---- kernel B: 32x32x16 MFMA MLP, 2 pts/pass, max-cover gather pipeline ---
// r15: phi(g,j) k-relabeling -> relayout = 8 pack2, zero cross-lane ops.
// r16: (256,4) killed the spill; dur unchanged -> latency-bound.
// r17: 4-deep gather pipeline: -6%. r18: DPP softmax + LOADL hoist: neutral.
//      Counter scale check: MfmaUtil/VALUBusy are CU-level (x4); per-SIMD
//      VALU ~41% => ~50us of stall at 3.4 waves/SIMD. Remaining exposed
//      latency = Z/Pf random gather with only L4+epilogue of cover.
// r19: (a) Y/Z stored as packed bf16 (u32 pairs): gather bytes halved,
//      Z region 9.4->4.7MB => largely L2-resident; carries 32->16 regs.
//      (b) prefetches moved to right after L1 (cover = L2+L3+L4+epilogue).
// r20: resubmit (r19 never ran: container infra failure).
#define LOADL(Lc)                                                             \
    {                                                                         \
        A0l = *(const short8*)&wfrag[(Lc)][0][1][lane + io][0];               \
        A0h = *(const short8*)&wfrag[(Lc)][0][0][lane + io][0];               \
        A1l = *(const short8*)&wfrag[(Lc)][1][1][lane + io][0];               \
        A1h = *(const short8*)&wfrag[(Lc)][1][0][lane + io][0];               \
        bq0 = *(const f4*)&btl[(Lc) * 32 +      4 * hi + 4 * io];             \
        bq1 = *(const f4*)&btl[(Lc) * 32 +  8 + 4 * hi + 4 * io];             \
        bq2 = *(const f4*)&btl[(Lc) * 32 + 16 + 4 * hi + 4 * io];             \
        bq3 = *(const f4*)&btl[(Lc) * 32 + 24 + 4 * hi + 4 * io];             \
    }

#define LAYER_MM(ACCV, BIN0, BIN1)                                            \
    {                                                                         \
        ACCV[0]  = bq0[0]; ACCV[1]  = bq0[1]; ACCV[2]  = bq0[2]; ACCV[3]  = bq0[3]; \
        ACCV[4]  = bq1[0]; ACCV[5]  = bq1[1]; ACCV[6]  = bq1[2]; ACCV[7]  = bq1[3]; \
        ACCV[8]  = bq2[0]; ACCV[9]  = bq2[1]; ACCV[10] = bq2[2]; ACCV[11] = bq2[3]; \
        ACCV[12] = bq3[0]; ACCV[13] = bq3[1]; ACCV[14] = bq3[2]; ACCV[15] = bq3[3]; \
        ACCV = mm32(A0l, BIN0.v, ACCV);                                       \
        ACCV = mm32(A0h, BIN0.v, ACCV);                                       \
        ACCV = mm32(A1l, BIN1.v, ACCV);                                       \
        ACCV = mm32(A1h, BIN1.v, ACCV);                                       \
    }

// C regs (gelu'd, register order == phi order) -> next-layer B fragments.
#define RELAYOUT(SRC, B0V, B1V)                                               \
    {                                                                         \
        B0V.u[0] = pack2(SRC[0],  SRC[1]);                                    \
        B0V.u[1] = pack2(SRC[2],  SRC[3]);                                    \
        B0V.u[2] = pack2(SRC[4],  SRC[5]);                                    \
        B0V.u[3] = pack2(SRC[6],  SRC[7]);                                    \
        B1V.u[0] = pack2(SRC[8],  SRC[9]);                                    \
        B1V.u[1] = pack2(SRC[10], SRC[11]);                                   \
        B1V.u[2] = pack2(SRC[12], SRC[13]);                                   \
        B1V.u[3] = pack2(SRC[14], SRC[15]);                                   \
    }

__global__ __launch_bounds__(256, 4) void main_kernel(
    const float* __restrict__ Pf, const float* __restrict__ Of,
    const int* __restrict__ args,
    const float* __restrict__ W1, const float* __restrict__ g1,
    const float* __restrict__ v1,
    const float* __restrict__ W2, const float* __restrict__ g2,
    const float* __restrict__ b2, const float* __restrict__ m2,
    const float* __restrict__ v2,
    const float* __restrict__ W3, const float* __restrict__ g3,
    const float* __restrict__ b3, const float* __restrict__ m3,
    const float* __restrict__ v3,
    const float* __restrict__ W4, const float* __restrict__ g4,
    const float* __restrict__ b4, const float* __restrict__ m4,
    const float* __restrict__ v4,
    const float* __restrict__ Wc, const float* __restrict__ bc,
    const float* __restrict__ ws, float* __restrict__ out)
{
    __shared__ __align__(16) unsigned wfrag[3][2][2][64][4]; // L,khalf,hi/lo,lane,pair
    __shared__ __align__(16) float btl[3 * 32];   // BN beta by [L][ch]
    __shared__ __align__(16) float wch[3 * 32];   // Wc rows A,B,O by ch
    __shared__ __align__(16) float w1t[2 * 32];   // W1 cols 65,66 folded, by ch
    __shared__ float bcs[3];
    __shared__ int   izs;

    const float* Ws[3] = {W2, W3, W4};
    const float* gs[3] = {g2, g3, g4};
    const float* vs[3] = {v2, v3, v4};
    const float* bs[3] = {b2, b3, b4};
    const float* ms[3] = {m2, m3, m4};

    for (int idx = threadIdx.x; idx < 1536; idx += 256) {
        int pp  = idx & 3;
        int ln  = (idx >> 2) & 63;
        int kh  = (idx >> 8) & 1;
        int L   = idx >> 9;
        int row = ln & 31;
        int g   = ln >> 5;
        // phi(g, e) = 4g + (e&3) + 8*(e>>2); pair pp covers elems 2pp, 2pp+1
        int k   = kh * 16 + 4 * g + 2 * (pp & 1) + 8 * (pp >> 1);
        float inv = gs[L][row] * rsqrtf(vs[L][row] + 1e-5f);
        float w0 = Ws[L][row * 32 + k]     * inv;
        float w1 = Ws[L][row * 32 + k + 1] * inv;
        unsigned hiw, low;
        split_pack(w0, w1, hiw, low);
        wfrag[L][kh][0][ln][pp] = hiw;
        wfrag[L][kh][1][ln][pp] = low;
    }
    if (threadIdx.x < 96) {
        int L = threadIdx.x >> 5, ch = threadIdx.x & 31;
        btl[threadIdx.x] = bs[L][ch] - ms[L][ch] * (gs[L][ch] * rsqrtf(vs[L][ch] + 1e-5f));
        wch[threadIdx.x] = Wc[L * 32 + ch];
    }
    if (threadIdx.x < 64) {
        int t = threadIdx.x >> 5, ch = threadIdx.x & 31;
        float i1 = g1[ch] * rsqrtf(v1[ch] + 1e-5f);
        w1t[threadIdx.x] = W1[ch * 67 + 65 + t] * i1;
    }
    if (threadIdx.x < 3) bcs[threadIdx.x] = bc[threadIdx.x];
    if (threadIdx.x == 0) izs = (int)(args[0] >> 16);   // == 0, opaque
    __syncthreads();

    const unsigned* wsu = (const unsigned*)ws;
    const int lane  = threadIdx.x & 63;
    const int wid   = threadIdx.x >> 6;
    const int m     = lane & 15;          // m-index (softmax axis)
    const int pt    = (lane >> 4) & 1;    // which of the 2 points in the pass
    const int hi    = lane >> 5;          // k-group
    const int q4    = hi << 2;            // 4*hi
    const int izero = izs;                // 0, compiler-opaque

    const int base  = blockIdx.x * 32 + wid * 8 + pt;   // 4 iterations x stride 2

    // ---- pipeline carries (loaded for iter 0 here; refilled post-L1) ------
    uint4v yu0, yu1, zu0, zu1;
    float of0v, of1v, pfg_n;
    int   aI_n;
    {
        const int C0 = base;
        const int b0 = (C0 >= NN) ? 1 : 0;
        const int n0 = C0 - b0 * NN;
        const int a0 = args[(b0 * NUMM + m) * NN + n0];
        of0v = Of[((b0 * 2 + 0) * NUMM + m) * NN + n0];
        of1v = Of[((b0 * 2 + 1) * NUMM + m) * NN + n0];
        pfg_n = Pf[b0 * NN + a0];
        const uint4v* yb = (const uint4v*)(wsu + (size_t)(b0 * NN + n0) * 16 + hi * 8);
        const uint4v* zb = (const uint4v*)(wsu + ZOFSU + (size_t)(b0 * NN + a0) * 16 + hi * 8);
        yu0 = yb[0]; yu1 = yb[1];
        zu0 = zb[0]; zu1 = zb[1];
        // args for iter 1
        const int C1 = (C0 + 2 < BB * NN) ? C0 + 2 : BB * NN - 1;
        const int b1_ = (C1 >= NN) ? 1 : 0;
        const int n1_ = C1 - b1_ * NN;
        aI_n = args[(b1_ * NUMM + m) * NN + n1_];
    }

#pragma unroll 1
    for (int i = 0; i < 4; i++) {
        const int io = i & izero;                         // 0 every iter, unprovable
        const int C  = base + i * 2;
        const int b  = (C >= NN) ? 1 : 0;
        const int n  = C - b * NN;
        const float pfg = pfg_n;                          // consumed in epilogue

        short8 A0l, A0h, A1l, A1h;
        f4 bq0, bq1, bq2, bq3;
        LOADL(0);                                         // covered by L1 math

        f4 wa[4], wb[4];
        wa[0] = *(const f4*)&w1t[q4 + 4 * io];
        wa[1] = *(const f4*)&w1t[8 + q4 + 4 * io];
        wa[2] = *(const f4*)&w1t[16 + q4 + 4 * io];
        wa[3] = *(const f4*)&w1t[24 + q4 + 4 * io];
        wb[0] = *(const f4*)&w1t[32 + q4 + 4 * io];
        wb[1] = *(const f4*)&w1t[40 + q4 + 4 * io];
        wb[2] = *(const f4*)&w1t[48 + q4 + 4 * io];
        wb[3] = *(const f4*)&w1t[56 + q4 + 4 * io];

        // ---- layer 1: h1 = gelu(Y+Z+of terms) -> directly the B fragments --
        // u32 j = q*2+pair holds channels (8q+4hi+2pair) + {lo,hi}
        float x[16];
#pragma unroll
        for (int q = 0; q < 4; q++) {
            const unsigned ya0 = (q < 2) ? yu0[2 * q]     : yu1[2 * q - 4];
            const unsigned ya1 = (q < 2) ? yu0[2 * q + 1] : yu1[2 * q - 3];
            const unsigned za0 = (q < 2) ? zu0[2 * q]     : zu1[2 * q - 4];
            const unsigned za1 = (q < 2) ? zu0[2 * q + 1] : zu1[2 * q - 3];
            x[4 * q + 0] = fmaf(of1v, wb[q][0], fmaf(of0v, wa[q][0], bflo(ya0) + bflo(za0)));
            x[4 * q + 1] = fmaf(of1v, wb[q][1], fmaf(of0v, wa[q][1], bfhi(ya0) + bfhi(za0)));
            x[4 * q + 2] = fmaf(of1v, wb[q][2], fmaf(of0v, wa[q][2], bflo(ya1) + bflo(za1)));
            x[4 * q + 3] = fmaf(of1v, wb[q][3], fmaf(of0v, wa[q][3], bfhi(ya1) + bfhi(za1)));
        }
#pragma unroll
        for (int j = 0; j < 16; j++) x[j] = gelu_fast(x[j]);
        UV B0, B1;
        RELAYOUT(x, B0, B1);

        // ---- max-cover prefetch for iter i+1 (consumed at next L1) --------
        {
            const int Cn = (C + 2 < BB * NN) ? C + 2 : BB * NN - 1;
            const int bn = (Cn >= NN) ? 1 : 0;
            const int nn = Cn - bn * NN;
            const uint4v* ybn = (const uint4v*)(wsu + (size_t)(bn * NN + nn) * 16 + hi * 8);
            yu0 = ybn[0]; yu1 = ybn[1];
            of0v = Of[((bn * 2 + 0) * NUMM + m) * NN + nn];
            of1v = Of[((bn * 2 + 1) * NUMM + m) * NN + nn];
            const int aN = aI_n;
            pfg_n = Pf[bn * NN + aN];
            const uint4v* zbn = (const uint4v*)(wsu + ZOFSU + (size_t)(bn * NN + aN) * 16 + hi * 8);
            zu0 = zbn[0]; zu1 = zbn[1];
            const int Ca = (C + 4 < BB * NN) ? C + 4 : BB * NN - 1;
            const int ba = (Ca >= NN) ? 1 : 0;
            const int na = Ca - ba * NN;
            aI_n = args[(ba * NUMM + m) * NN + na];
        }

        // ---- layer 2 ----
        f16v acc;
        LAYER_MM(acc, B0, B1);
        LOADL(1);                                         // covered by gelu(h2)
        float h2g[16];
#pragma unroll
        for (int r = 0; r < 16; r++) h2g[r] = gelu_fast(acc[r]);
        RELAYOUT(h2g, B0, B1);

        // ---- layer 3 ----
        LAYER_MM(acc, B0, B1);
        LOADL(2);                                         // covered by gelu(h3)
        float h3g[16];
#pragma unroll
        for (int r = 0; r < 16; r++) h3g[r] = gelu_fast(acc[r]);
        RELAYOUT(h3g, B0, B1);

        // ---- layer 4 + residual + head (all in C layout) ----
        LAYER_MM(acc, B0, B1);

        float pa = 0.0f, pb = 0.0f, po = 0.0f;
#pragma unroll
        for (int q = 0; q < 4; q++) {
            const f4 wAq = *(const f4*)&wch[      8 * q + q4 + 4 * io];
            const f4 wBq = *(const f4*)&wch[32 +  8 * q + q4 + 4 * io];
            const f4 wOq = *(const f4*)&wch[64 +  8 * q + q4 + 4 * io];
#pragma unroll
            for (int r2 = 0; r2 < 4; r2++) {
                float xf = gelu_fast(h2g[4 * q + r2] + acc[4 * q + r2]);
                pa = fmaf(wAq[r2], xf, pa);
                pb = fmaf(wBq[r2], xf, pb);
                po = fmaf(wOq[r2], xf, po);
            }
        }
        // partner half (lane^32) holds the other 16 channels (LDS pipe, 3 parallel)
        pa += __shfl_xor(pa, 32, 64);
        pb += __shfl_xor(pb, 32, 64);
        po += __shfl_xor(po, 32, 64);

        const float alpha = pa + bcs[0];
        const float beta_ = pb + bcs[1];
        const float omega = po + bcs[2];
        const float val = fmaf(alpha + 1.0f, pfg, beta_);

        // softmax over the 16 m's — DPP row reductions (VALU latency)
        float mx = dpp_max<0xB1>(omega);
        mx = dpp_max<0x4E>(mx);
        mx = dpp_max<0x141>(mx);
        mx = dpp_max<0x140>(mx);
        const float e = __expf(omega - mx);
        float S = e, T = val * e;
        S = dpp_add<0xB1>(S);   T = dpp_add<0xB1>(T);
        S = dpp_add<0x4E>(S);   T = dpp_add<0x4E>(T);
        S = dpp_add<0x141>(S);  T = dpp_add<0x141>(T);
        S = dpp_add<0x140>(S);  T = dpp_add<0x140>(T);

        if ((lane & 15) == 0 && lane < 32)
            out[b * NN + n] = T * __builtin_amdgcn_rcpf(S);
    }
}

// ---- launcher ---------------------------------------------------------------
extern "C" void kernel_launch(void* const* d_in, const int* in_sizes, int n_in,
                              void* d_out, int out_size, void* d_ws, size_t ws_size,
                              hipStream_t stream) {
    const float* If    = (const float*)d_in[0];
    const float* Pf    = (const float*)d_in[1];
    const float* Of    = (const float*)d_in[2];
    const int*   args  = (const int*)d_in[3];
    const float* W1    = (const float*)d_in[4];
    const float* g1    = (const float*)d_in[5];
    const float* b1    = (const float*)d_in[6];
    const float* m1    = (const float*)d_in[7];
    const float* v1    = (const float*)d_in[8];
    const float* W2    = (const float*)d_in[9];
    const float* g2    = (const float*)d_in[10];
    const float* b2    = (const float*)d_in[11];
    const float* m2    = (const float*)d_in[12];
    const float* v2    = (const float*)d_in[13];
    const float* W3    = (const float*)d_in[14];
    const float* g3    = (const float*)d_in[15];
    const float* b3    = (const float*)d_in[16];
    const float* m3    = (const float*)d_in[17];
    const float* v3    = (const float*)d_in[18];
    const float* W4    = (const float*)d_in[19];
    const float* g4    = (const float*)d_in[20];
    const float* b4    = (const float*)d_in[21];
    const float* m4    = (const float*)d_in[22];
    const float* v4    = (const float*)d_in[23];
    const float* Wc    = (const float*)d_in[24];
    const float* bc    = (const float*)d_in[25];

    float* ws  = (float*)d_ws;
    float* out = (float*)d_out;

    yz_kernel<<<(BB * NN) / 64, 256, 0, stream>>>(
        If, Pf, W1, g1, b1, m1, v1, ws);

    main_kernel<<<(BB * NN) / 32, 256, 0, stream>>>(
        Pf, Of, args,
        W1, g1, v1,
        W2, g2, b2, m2, v2,
        W3, g3, b3, m3, v3,
        W4, g4, b4, m4, v4,
        Wc, bc, ws, out);
}

// Round 8
// 225.384 us; speedup vs baseline: 1.0333x; 1.0058x over previous
//
#include <hip/hip_runtime.h>
#include <math.h>

#define BB   2
#define CFI  32
#define NN   36864          // 192*192
#define NUMM 16

// workspace (packed bf16 pairs): Y at wsu[0..], Z at wsu[ZOFSU..]
// per point: 16 u32 = 32 channels. u32 idx = hi*8 + q*2 + pair,
// channel c = 8q + 4hi + 2pair + {lo,hi16}.
#define ZOFSU (BB * NN * 16)

typedef __attribute__((ext_vector_type(8))) short short8;   // 8 bf16 (4 VGPRs)
typedef __attribute__((ext_vector_type(4))) float f4;       // 4 f32
typedef __attribute__((ext_vector_type(16))) float f16v;    // 16 f32 (32x32 acc)
typedef __attribute__((ext_vector_type(4))) unsigned uint4v;
typedef __attribute__((ext_vector_type(2))) unsigned u2v;

static __device__ __forceinline__ f16v mm32(short8 a, short8 b, f16v c) {
    return __builtin_amdgcn_mfma_f32_32x32x16_bf16(a, b, c, 0, 0, 0);
}

// DPP-based 16-lane-row reductions (VALU latency, no LDS pipe).
template <int CTRL>
static __device__ __forceinline__ float dpp_add(float x) {
    int y = __builtin_amdgcn_update_dpp(0, __builtin_bit_cast(int, x),
                                        CTRL, 0xf, 0xf, true);
    return x + __builtin_bit_cast(float, y);
}
template <int CTRL>
static __device__ __forceinline__ float dpp_max(float x) {
    int y = __builtin_amdgcn_update_dpp(0, __builtin_bit_cast(int, x),
                                        CTRL, 0xf, 0xf, true);
    return fmaxf(x, __builtin_bit_cast(float, y));
}

// tanh-form gelu: x * sigmoid(1.595769x + 0.0713548x^3), exp2-folded.
static __device__ __forceinline__ float gelu_fast(float x) {
    const float x2  = x * x;
    const float q   = fmaf(-0.10294310f, x2, -2.30211813f);
    const float e   = exp2f(q * x);
    const float r   = __builtin_amdgcn_rcpf(e + 1.0f);
    return x * r;
}

static __device__ __forceinline__ unsigned bf16_rne_bits(float x) {
    unsigned u = __builtin_bit_cast(unsigned, x);
    return u + 0x7fffu + ((u >> 16) & 1u);
}
static __device__ __forceinline__ void split_pack(float x0, float x1,
                                                  unsigned& hi, unsigned& lo) {
    unsigned r0 = bf16_rne_bits(x0);
    unsigned r1 = bf16_rne_bits(x1);
    float h0 = __builtin_bit_cast(float, r0 & 0xffff0000u);
    float h1 = __builtin_bit_cast(float, r1 & 0xffff0000u);
    hi = (r0 >> 16) | (r1 & 0xffff0000u);
    unsigned s0 = bf16_rne_bits(x0 - h0);
    unsigned s1 = bf16_rne_bits(x1 - h1);
    lo = (s0 >> 16) | (s1 & 0xffff0000u);
}

// cheap round-half-up bf16 pair pack (activations / workspace)
static __device__ __forceinline__ unsigned pack2(float a, float b) {
    unsigned ua = __builtin_bit_cast(unsigned, a) + 0x8000u;
    unsigned ub = __builtin_bit_cast(unsigned, b) + 0x8000u;
    return (ua >> 16) | (ub & 0xffff0000u);
}
static __device__ __forceinline__ float bflo(unsigned u) {
    return __builtin_bit_cast(float, u << 16);
}
static __device__ __forceinline__ float bfhi(unsigned u) {
    return __builtin_bit_cast(float, u & 0xffff0000u);
}

union UV { unsigned u[4]; short8 v; };

// ---- kernel A: per-point Y/Z precompute, packed-bf16 output ---------------
__global__ __launch_bounds__(256) void yz_kernel(
    const float* __restrict__ If, const float* __restrict__ Pf,
    const float* __restrict__ W1, const float* __restrict__ g1,
    const float* __restrict__ b1, const float* __restrict__ m1,
    const float* __restrict__ v1,
    float* __restrict__ wsYZ)
{
    __shared__ float wy[1024], wz[1024], wp[32], bt1[32];
    for (int i = threadIdx.x; i < 1024; i += 256) {
        int o = i >> 5, c = i & 31;
        float inv = g1[o] * rsqrtf(v1[o] + 1e-5f);
        wy[i] = W1[o * 67 + c]      * inv;
        wz[i] = W1[o * 67 + 32 + c] * inv;
    }
    if (threadIdx.x < 32) {
        int o = threadIdx.x;
        float inv = g1[o] * rsqrtf(v1[o] + 1e-5f);
        wp[o]  = W1[o * 67 + 64] * inv;
        bt1[o] = b1[o] - m1[o] * inv;
    }
    __syncthreads();

    const int r  = threadIdx.x & 3;
    const int p  = blockIdx.x * 64 + (threadIdx.x >> 2);
    const int b  = p / NN, n = p - b * NN;
    const int o0 = r * 8;
    const float* ifp = If + (size_t)b * CFI * NN + n;

    float v[32];
#pragma unroll
    for (int c = 0; c < 32; c++) v[c] = ifp[(size_t)c * NN];
    const float pf = Pf[p];

    float accY[8], accZ[8];
#pragma unroll
    for (int j = 0; j < 8; j++) {
        const float4* wyr = (const float4*)&wy[(o0 + j) * 32];
        const float4* wzr = (const float4*)&wz[(o0 + j) * 32];
        float ay = bt1[o0 + j];
        float az = wp[o0 + j] * pf;
#pragma unroll
        for (int c4 = 0; c4 < 8; c4++) {
            float4 a = wyr[c4], z = wzr[c4];
            ay = fmaf(a.x, v[4 * c4 + 0], ay);  az = fmaf(z.x, v[4 * c4 + 0], az);
            ay = fmaf(a.y, v[4 * c4 + 1], ay);  az = fmaf(z.y, v[4 * c4 + 1], az);
            ay = fmaf(a.z, v[4 * c4 + 2], ay);  az = fmaf(z.z, v[4 * c4 + 2], az);
            ay = fmaf(a.w, v[4 * c4 + 3], ay);  az = fmaf(z.w, v[4 * c4 + 3], az);
        }
        accY[j] = ay; accZ[j] = az;
    }

    // pack to bf16 pairs. thread r owns channels c = 8r + j (q == r):
    // j=0..3 -> hi=0 (u32 idx 2r, 2r+1), j=4..7 -> hi=1 (idx 8+2r, 8+2r+1).
    unsigned* wsu = (unsigned*)wsYZ;
    u2v yA, yB, zA, zB;
    yA[0] = pack2(accY[0], accY[1]); yA[1] = pack2(accY[2], accY[3]);
    yB[0] = pack2(accY[4], accY[5]); yB[1] = pack2(accY[6], accY[7]);
    zA[0] = pack2(accZ[0], accZ[1]); zA[1] = pack2(accZ[2], accZ[3]);
    zB[0] = pack2(accZ[4], accZ[5]); zB[1] = pack2(accZ[6], accZ[7]);
    *(u2v*)(wsu + (size_t)p * 16 + 2 * r)          = yA;
    *(u2v*)(wsu + (size_t)p * 16 + 8 + 2 * r)      = yB;
    *(u2v*)(wsu + ZOFSU + (size_t)p * 16 + 2 * r)     = zA;
    *(u2v*)(wsu + ZOFSU + (size_t)p * 16 + 8 + 2 * r) = zB;
}

// ---- kernel B: 32x32x16 MFMA MLP, 2 pts/pass, max-cover pipeline ----------
// r15: phi(g,j) k-relabeling -> relayout = 8 pack2, zero cross-lane ops.
// r16: (256,4) killed the spill; dur unchanged -> latency-bound.
// r17: gather pipeline -6%. r18: DPP/hoist neutral. r19/20: bf16 Y/Z
//      (FETCH 75->44MB) neutral => bytes/residency not the wall.
// r21: counters are CU-SUMMED (MfmaUtil math matches exactly): per-SIMD
//      VALU 22%, LDS 36%, MFMA 6% -- nothing saturated, wall = latency x
//      under-occupancy (3.4 waves/SIMD, capped by our own bounds).
//      => TLP push: (256,5). Slim ~24 regs to fit the 102-reg budget:
//      fuse gelu+pack pairwise (kills x[16]/h2g[16]/h3g[16] temporaries);
//      keep residual h2 as packed bf16 P0/P1 (8 regs), unpack at epilogue
//      (residual now uses bf16(h2) == L3's actual input; +<=0.004 abs).
//      Tripwire: WRITE_SIZE must stay <1MB, else revert bounds.
#define LOADL(Lc)                                                             \
    {                                                                         \
        A0l = *(const short8*)&wfrag[(Lc)][0][1][lane + io][0];               \
        A0h = *(const short8*)&wfrag[(Lc)][0][0][lane + io][0];               \
        A1l = *(const short8*)&wfrag[(Lc)][1][1][lane + io][0];               \
        A1h = *(const short8*)&wfrag[(Lc)][1][0][lane + io][0];               \
        bq0 = *(const f4*)&btl[(Lc) * 32 +      4 * hi + 4 * io];             \
        bq1 = *(const f4*)&btl[(Lc) * 32 +  8 + 4 * hi + 4 * io];             \
        bq2 = *(const f4*)&btl[(Lc) * 32 + 16 + 4 * hi + 4 * io];             \
        bq3 = *(const f4*)&btl[(Lc) * 32 + 24 + 4 * hi + 4 * io];             \
    }

#define LAYER_MM(ACCV, BIN0, BIN1)                                            \
    {                                                                         \
        ACCV[0]  = bq0[0]; ACCV[1]  = bq0[1]; ACCV[2]  = bq0[2]; ACCV[3]  = bq0[3]; \
        ACCV[4]  = bq1[0]; ACCV[5]  = bq1[1]; ACCV[6]  = bq1[2]; ACCV[7]  = bq1[3]; \
        ACCV[8]  = bq2[0]; ACCV[9]  = bq2[1]; ACCV[10] = bq2[2]; ACCV[11] = bq2[3]; \
        ACCV[12] = bq3[0]; ACCV[13] = bq3[1]; ACCV[14] = bq3[2]; ACCV[15] = bq3[3]; \
        ACCV = mm32(A0l, BIN0.v, ACCV);                                       \
        ACCV = mm32(A0h, BIN0.v, ACCV);                                       \
        ACCV = mm32(A1l, BIN1.v, ACCV);                                       \
        ACCV = mm32(A1h, BIN1.v, ACCV);                                       \
    }

// gelu + pack the 16 acc values pairwise into B fragments (2-reg transients).
#define GELU_PACK(ACCV, B0V, B1V)                                             \
    {                                                                         \
        _Pragma("unroll")                                                     \
        for (int k = 0; k < 4; k++) {                                         \
            float t0 = gelu_fast(ACCV[2 * k]);                                \
            float t1 = gelu_fast(ACCV[2 * k + 1]);                            \
            B0V.u[k] = pack2(t0, t1);                                         \
            float t2 = gelu_fast(ACCV[8 + 2 * k]);                            \
            float t3 = gelu_fast(ACCV[8 + 2 * k + 1]);                        \
            B1V.u[k] = pack2(t2, t3);                                         \
        }                                                                     \
    }

__global__ __launch_bounds__(256, 5) void main_kernel(
    const float* __restrict__ Pf, const float* __restrict__ Of,
    const int* __restrict__ args,
    const float* __restrict__ W1, const float* __restrict__ g1,
    const float* __restrict__ v1,
    const float* __restrict__ W2, const float* __restrict__ g2,
    const float* __restrict__ b2, const float* __restrict__ m2,
    const float* __restrict__ v2,
    const float* __restrict__ W3, const float* __restrict__ g3,
    const float* __restrict__ b3, const float* __restrict__ m3,
    const float* __restrict__ v3,
    const float* __restrict__ W4, const float* __restrict__ g4,
    const float* __restrict__ b4, const float* __restrict__ m4,
    const float* __restrict__ v4,
    const float* __restrict__ Wc, const float* __restrict__ bc,
    const float* __restrict__ ws, float* __restrict__ out)
{
    __shared__ __align__(16) unsigned wfrag[3][2][2][64][4]; // L,khalf,hi/lo,lane,pair
    __shared__ __align__(16) float btl[3 * 32];   // BN beta by [L][ch]
    __shared__ __align__(16) float wch[3 * 32];   // Wc rows A,B,O by ch
    __shared__ __align__(16) float w1t[2 * 32];   // W1 cols 65,66 folded, by ch
    __shared__ float bcs[3];
    __shared__ int   izs;

    const float* Ws[3] = {W2, W3, W4};
    const float* gs[3] = {g2, g3, g4};
    const float* vs[3] = {v2, v3, v4};
    const float* bs[3] = {b2, b3, b4};
    const float* ms[3] = {m2, m3, m4};

    for (int idx = threadIdx.x; idx < 1536; idx += 256) {
        int pp  = idx & 3;
        int ln  = (idx >> 2) & 63;
        int kh  = (idx >> 8) & 1;
        int L   = idx >> 9;
        int row = ln & 31;
        int g   = ln >> 5;
        // phi(g, e) = 4g + (e&3) + 8*(e>>2); pair pp covers elems 2pp, 2pp+1
        int k   = kh * 16 + 4 * g + 2 * (pp & 1) + 8 * (pp >> 1);
        float inv = gs[L][row] * rsqrtf(vs[L][row] + 1e-5f);
        float w0 = Ws[L][row * 32 + k]     * inv;
        float w1 = Ws[L][row * 32 + k + 1] * inv;
        unsigned hiw, low;
        split_pack(w0, w1, hiw, low);
        wfrag[L][kh][0][ln][pp] = hiw;
        wfrag[L][kh][1][ln][pp] = low;
    }
    if (threadIdx.x < 96) {
        int L = threadIdx.x >> 5, ch = threadIdx.x & 31;
        btl[threadIdx.x] = bs[L][ch] - ms[L][ch] * (gs[L][ch] * rsqrtf(vs[L][ch] + 1e-5f));
        wch[threadIdx.x] = Wc[L * 32 + ch];
    }
    if (threadIdx.x < 64) {
        int t = threadIdx.x >> 5, ch = threadIdx.x & 31;
        float i1 = g1[ch] * rsqrtf(v1[ch] + 1e-5f);
        w1t[threadIdx.x] = W1[ch * 67 + 65 + t] * i1;
    }
    if (threadIdx.x < 3) bcs[threadIdx.x] = bc[threadIdx.x];
    if (threadIdx.x == 0) izs = (int)(args[0] >> 16);   // == 0, opaque
    __syncthreads();

    const unsigned* wsu = (const unsigned*)ws;
    const int lane  = threadIdx.x & 63;
    const int wid   = threadIdx.x >> 6;
    const int m     = lane & 15;          // m-index (softmax axis)
    const int pt    = (lane >> 4) & 1;    // which of the 2 points in the pass
    const int hi    = lane >> 5;          // k-group
    const int q4    = hi << 2;            // 4*hi
    const int izero = izs;                // 0, compiler-opaque

    const int base  = blockIdx.x * 32 + wid * 8 + pt;   // 4 iterations x stride 2

    // ---- pipeline carries (loaded for iter 0 here; refilled post-L1) ------
    uint4v yu0, yu1, zu0, zu1;
    float of0v, of1v, pfg_n;
    int   aI_n;
    {
        const int C0 = base;
        const int b0 = (C0 >= NN) ? 1 : 0;
        const int n0 = C0 - b0 * NN;
        const int a0 = args[(b0 * NUMM + m) * NN + n0];
        of0v = Of[((b0 * 2 + 0) * NUMM + m) * NN + n0];
        of1v = Of[((b0 * 2 + 1) * NUMM + m) * NN + n0];
        pfg_n = Pf[b0 * NN + a0];
        const uint4v* yb = (const uint4v*)(wsu + (size_t)(b0 * NN + n0) * 16 + hi * 8);
        const uint4v* zb = (const uint4v*)(wsu + ZOFSU + (size_t)(b0 * NN + a0) * 16 + hi * 8);
        yu0 = yb[0]; yu1 = yb[1];
        zu0 = zb[0]; zu1 = zb[1];
        // args for iter 1
        const int C1 = (C0 + 2 < BB * NN) ? C0 + 2 : BB * NN - 1;
        const int b1_ = (C1 >= NN) ? 1 : 0;
        const int n1_ = C1 - b1_ * NN;
        aI_n = args[(b1_ * NUMM + m) * NN + n1_];
    }

#pragma unroll 1
    for (int i = 0; i < 4; i++) {
        const int io = i & izero;                         // 0 every iter, unprovable
        const int C  = base + i * 2;
        const int b  = (C >= NN) ? 1 : 0;
        const int n  = C - b * NN;
        const float pfg = pfg_n;                          // consumed in epilogue

        short8 A0l, A0h, A1l, A1h;
        f4 bq0, bq1, bq2, bq3;
        LOADL(0);                                         // covered by L1 math

        // ---- layer 1: h1 = gelu(Y+Z+of terms) -> B fragments (fused pack) --
        // u32 j = q*2+pair holds channels (8q+4hi+2pair) + {lo,hi}
        UV B0, B1;
#pragma unroll
        for (int q = 0; q < 4; q++) {
            const f4 waq = *(const f4*)&w1t[8 * q + q4 + 4 * io];
            const f4 wbq = *(const f4*)&w1t[32 + 8 * q + q4 + 4 * io];
            const unsigned ya0 = (q < 2) ? yu0[2 * q]     : yu1[2 * q - 4];
            const unsigned ya1 = (q < 2) ? yu0[2 * q + 1] : yu1[2 * q - 3];
            const unsigned za0 = (q < 2) ? zu0[2 * q]     : zu1[2 * q - 4];
            const unsigned za1 = (q < 2) ? zu0[2 * q + 1] : zu1[2 * q - 3];
            float t0 = fmaf(of1v, wbq[0], fmaf(of0v, waq[0], bflo(ya0) + bflo(za0)));
            float t1 = fmaf(of1v, wbq[1], fmaf(of0v, waq[1], bfhi(ya0) + bfhi(za0)));
            float t2 = fmaf(of1v, wbq[2], fmaf(of0v, waq[2], bflo(ya1) + bflo(za1)));
            float t3 = fmaf(of1v, wbq[3], fmaf(of0v, waq[3], bfhi(ya1) + bfhi(za1)));
            t0 = gelu_fast(t0); t1 = gelu_fast(t1);
            t2 = gelu_fast(t2); t3 = gelu_fast(t3);
            const unsigned lo2 = pack2(t0, t1), hi2 = pack2(t2, t3);
            if (q < 2) { B0.u[2 * q] = lo2; B0.u[2 * q + 1] = hi2; }
            else       { B1.u[2 * q - 4] = lo2; B1.u[2 * q - 3] = hi2; }
        }

        // ---- max-cover prefetch for iter i+1 (consumed at next L1) --------
        {
            const int Cn = (C + 2 < BB * NN) ? C + 2 : BB * NN - 1;
            const int bn = (Cn >= NN) ? 1 : 0;
            const int nn = Cn - bn * NN;
            const uint4v* ybn = (const uint4v*)(wsu + (size_t)(bn * NN + nn) * 16 + hi * 8);
            yu0 = ybn[0]; yu1 = ybn[1];
            of0v = Of[((bn * 2 + 0) * NUMM + m) * NN + nn];
            of1v = Of[((bn * 2 + 1) * NUMM + m) * NN + nn];
            const int aN = aI_n;
            pfg_n = Pf[bn * NN + aN];
            const uint4v* zbn = (const uint4v*)(wsu + ZOFSU + (size_t)(bn * NN + aN) * 16 + hi * 8);
            zu0 = zbn[0]; zu1 = zbn[1];
            const int Ca = (C + 4 < BB * NN) ? C + 4 : BB * NN - 1;
            const int ba = (Ca >= NN) ? 1 : 0;
            const int na = Ca - ba * NN;
            aI_n = args[(ba * NUMM + m) * NN + na];
        }

        // ---- layer 2 ----
        f16v acc;
        LAYER_MM(acc, B0, B1);
        LOADL(1);                                         // covered by gelu(h2)
        UV P0, P1;                                        // packed gelu(h2): L3 input + residual
        GELU_PACK(acc, P0, P1);
        B0 = P0; B1 = P1;

        // ---- layer 3 ----
        LAYER_MM(acc, B0, B1);
        LOADL(2);                                         // covered by gelu(h3)
        GELU_PACK(acc, B0, B1);

        // ---- layer 4 + residual + head (all in C layout) ----
        LAYER_MM(acc, B0, B1);

        float pa = 0.0f, pb = 0.0f, po = 0.0f;
#pragma unroll
        for (int q = 0; q < 4; q++) {
            const f4 wAq = *(const f4*)&wch[      8 * q + q4 + 4 * io];
            const f4 wBq = *(const f4*)&wch[32 +  8 * q + q4 + 4 * io];
            const f4 wOq = *(const f4*)&wch[64 +  8 * q + q4 + 4 * io];
            const unsigned pu0 = (q < 2) ? P0.u[2 * q]     : P1.u[2 * q - 4];
            const unsigned pu1 = (q < 2) ? P0.u[2 * q + 1] : P1.u[2 * q - 3];
            const float h20 = bflo(pu0), h21 = bfhi(pu0);
            const float h22 = bflo(pu1), h23 = bfhi(pu1);
            float xf0 = gelu_fast(h20 + acc[4 * q + 0]);
            float xf1 = gelu_fast(h21 + acc[4 * q + 1]);
            float xf2 = gelu_fast(h22 + acc[4 * q + 2]);
            float xf3 = gelu_fast(h23 + acc[4 * q + 3]);
            pa = fmaf(wAq[0], xf0, pa); pa = fmaf(wAq[1], xf1, pa);
            pa = fmaf(wAq[2], xf2, pa); pa = fmaf(wAq[3], xf3, pa);
            pb = fmaf(wBq[0], xf0, pb); pb = fmaf(wBq[1], xf1, pb);
            pb = fmaf(wBq[2], xf2, pb); pb = fmaf(wBq[3], xf3, pb);
            po = fmaf(wOq[0], xf0, po); po = fmaf(wOq[1], xf1, po);
            po = fmaf(wOq[2], xf2, po); po = fmaf(wOq[3], xf3, po);
        }
        // partner half (lane^32) holds the other 16 channels (LDS pipe, 3 parallel)
        pa += __shfl_xor(pa, 32, 64);
        pb += __shfl_xor(pb, 32, 64);
        po += __shfl_xor(po, 32, 64);

        const float alpha = pa + bcs[0];
        const float beta_ = pb + bcs[1];
        const float omega = po + bcs[2];
        const float val = fmaf(alpha + 1.0f, pfg, beta_);

        // softmax over the 16 m's — DPP row reductions (VALU latency)
        float mx = dpp_max<0xB1>(omega);
        mx = dpp_max<0x4E>(mx);
        mx = dpp_max<0x141>(mx);
        mx = dpp_max<0x140>(mx);
        const float e = __expf(omega - mx);
        float S = e, T = val * e;
        S = dpp_add<0xB1>(S);   T = dpp_add<0xB1>(T);
        S = dpp_add<0x4E>(S);   T = dpp_add<0x4E>(T);
        S = dpp_add<0x141>(S);  T = dpp_add<0x141>(T);
        S = dpp_add<0x140>(S);  T = dpp_add<0x140>(T);

        if ((lane & 15) == 0 && lane < 32)
            out[b * NN + n] = T * __builtin_amdgcn_rcpf(S);
    }
}

// ---- launcher ---------------------------------------------------------------
extern "C" void kernel_launch(void* const* d_in, const int* in_sizes, int n_in,
                              void* d_out, int out_size, void* d_ws, size_t ws_size,
                              hipStream_t stream) {
    const float* If    = (const float*)d_in[0];
    const float* Pf    = (const float*)d_in[1];
    const float* Of    = (const float*)d_in[2];
    const int*   args  = (const int*)d_in[3];
    const float* W1    = (const float*)d_in[4];
    const float* g1    = (const float*)d_in[5];
    const float* b1    = (const float*)d_in[6];
    const float* m1    = (const float*)d_in[7];
    const float* v1    = (const float*)d_in[8];
    const float* W2    = (const float*)d_in[9];
    const float* g2    = (const float*)d_in[10];
    const float* b2    = (const float*)d_in[11];
    const float* m2    = (const float*)d_in[12];
    const float* v2    = (const float*)d_in[13];
    const float* W3    = (const float*)d_in[14];
    const float* g3    = (const float*)d_in[15];
    const float* b3    = (const float*)d_in[16];
    const float* m3    = (const float*)d_in[17];
    const float* v3    = (const float*)d_in[18];
    const float* W4    = (const float*)d_in[19];
    const float* g4    = (const float*)d_in[20];
    const float* b4    = (const float*)d_in[21];
    const float* m4    = (const float*)d_in[22];
    const float* v4    = (const float*)d_in[23];
    const float* Wc    = (const float*)d_in[24];
    const float* bc    = (const float*)d_in[25];

    float* ws  = (float*)d_ws;
    float* out = (float*)d_out;

    yz_kernel<<<(BB * NN) / 64, 256, 0, stream>>>(
        If, Pf, W1, g1, b1, m1, v1, ws);

    main_kernel<<<(BB * NN) / 32, 256, 0, stream>>>(
        Pf, Of, args,
        W1, g1, v1,
        W2, g2, b2, m2, v2,
        W3, g3, b3, m3, v3,
        W4, g4, b4, m4, v4,
        Wc, bc, ws, out);
}